// Round 1
// baseline (5998.369 us; speedup 1.0000x reference)
//
#include <hip/hip_runtime.h>
#include <hip/hip_bf16.h>
#include <stdint.h>

#define DD 1024   // hidden dim
#define BB 4      // batch
#define TT 2048   // seq len
#define VV 16000  // vocab
#define LCH 32    // chunk length
#define CCH 64    // num chunks (TT/LCH)
#define NR 256    // BB*CCH lockstep rows

typedef __bf16 bf16_t;
typedef float f32x4_t __attribute__((ext_vector_type(4)));
typedef bf16_t bf16x8_t __attribute__((ext_vector_type(8)));

// ---------------- fp32 -> bf16 convert (lm_w) ----------------
__global__ __launch_bounds__(256) void k_cvt(const float* __restrict__ src,
                                             bf16_t* __restrict__ dst, int n4) {
  int i = blockIdx.x * blockDim.x + threadIdx.x;
  int stride = gridDim.x * blockDim.x;
  for (; i < n4; i += stride) {
    float4 v = ((const float4*)src)[i];
    union { ushort4 u; bf16_t h[4]; } p;
    p.h[0] = (bf16_t)v.x; p.h[1] = (bf16_t)v.y;
    p.h[2] = (bf16_t)v.z; p.h[3] = (bf16_t)v.w;
    ((ushort4*)dst)[i] = p.u;
  }
}

// ---------------- phase A delta=0: state = h_{cL} ----------------
__global__ __launch_bounds__(256) void k_gather0(const float* __restrict__ embed,
                                                 const int* __restrict__ ids,
                                                 float* __restrict__ out) {
  int r = blockIdx.x;            // 0..255 : r = b*64 + c
  int b = r >> 6, c = r & 63;
  int id = ids[b * TT + c * LCH];
  const float4* src = (const float4*)(embed + (size_t)id * DD);
  float4* dst = (float4*)(out + (size_t)r * DD);
  for (int i = threadIdx.x; i < DD / 4; i += blockDim.x) dst[i] = src[i];
}

// ---------------- one lockstep scan round: Sout = Sin@W^T + h[t(c,delta)] ----------------
// grid (32,8): 32x32 output tile per WG, 2x2 per thread, no LDS (W rows broadcast, L1 reuse)
template <bool WRITE_H>
__global__ __launch_bounds__(256) void k_round(const float* __restrict__ Sin,
                                               float* __restrict__ Sout,
                                               const float* __restrict__ Wm,
                                               const float* __restrict__ embed,
                                               const int* __restrict__ ids,
                                               int delta, bf16_t* __restrict__ hidden) {
  int tid = threadIdx.x;
  int ti = tid & 15;   // row pair (lane-fast -> W loads broadcast across 16 lanes)
  int tj = tid >> 4;   // col pair
  int r0 = blockIdx.y * 32, j0 = blockIdx.x * 32;
  int r_a = r0 + ti * 2, r_b = r_a + 1;
  int j_a = j0 + tj * 2, j_b = j_a + 1;
  const float* sa = Sin + (size_t)r_a * DD;
  const float* sb = Sin + (size_t)r_b * DD;
  const float* wa = Wm + (size_t)j_a * DD;
  const float* wb = Wm + (size_t)j_b * DD;
  float a00 = 0.f, a01 = 0.f, a10 = 0.f, a11 = 0.f;
#pragma unroll 4
  for (int k = 0; k < DD; k += 4) {
    float4 x0 = *(const float4*)(sa + k);
    float4 x1 = *(const float4*)(sb + k);
    float4 y0 = *(const float4*)(wa + k);
    float4 y1 = *(const float4*)(wb + k);
    a00 = fmaf(x0.x, y0.x, a00); a00 = fmaf(x0.y, y0.y, a00);
    a00 = fmaf(x0.z, y0.z, a00); a00 = fmaf(x0.w, y0.w, a00);
    a01 = fmaf(x0.x, y1.x, a01); a01 = fmaf(x0.y, y1.y, a01);
    a01 = fmaf(x0.z, y1.z, a01); a01 = fmaf(x0.w, y1.w, a01);
    a10 = fmaf(x1.x, y0.x, a10); a10 = fmaf(x1.y, y0.y, a10);
    a10 = fmaf(x1.z, y0.z, a10); a10 = fmaf(x1.w, y0.w, a10);
    a11 = fmaf(x1.x, y1.x, a11); a11 = fmaf(x1.y, y1.y, a11);
    a11 = fmaf(x1.z, y1.z, a11); a11 = fmaf(x1.w, y1.w, a11);
  }
  int b_a = r_a >> 6, c_a = r_a & 63, t_a = c_a * LCH + delta;
  int b_b = r_b >> 6, c_b = r_b & 63, t_b = c_b * LCH + delta;
  int id_a = ids[b_a * TT + t_a];
  int id_b = ids[b_b * TT + t_b];
  a00 += embed[(size_t)id_a * DD + j_a];
  a01 += embed[(size_t)id_a * DD + j_b];
  a10 += embed[(size_t)id_b * DD + j_a];
  a11 += embed[(size_t)id_b * DD + j_b];
  Sout[(size_t)r_a * DD + j_a] = a00;
  Sout[(size_t)r_a * DD + j_b] = a01;
  Sout[(size_t)r_b * DD + j_a] = a10;
  Sout[(size_t)r_b * DD + j_b] = a11;
  if (WRITE_H) {
    hidden[((size_t)b_a * TT + t_a) * DD + j_a] = (bf16_t)a00;
    hidden[((size_t)b_a * TT + t_a) * DD + j_b] = (bf16_t)a01;
    hidden[((size_t)b_b * TT + t_b) * DD + j_a] = (bf16_t)a10;
    hidden[((size_t)b_b * TT + t_b) * DD + j_b] = (bf16_t)a11;
  }
}

// ---------------- carry step c: carries[:,c] = W32 @ carries[:,c-1] + ends[:,c-1] ----------------
// 64 WGs x 256 thr; each wave: 4 cols j x 4 batch rows, K split over 64 lanes + shuffle reduce
__global__ __launch_bounds__(256) void k_carry(float* carries,
                                               const float* __restrict__ ends,
                                               const float* __restrict__ W32, int c) {
  int wave = threadIdx.x >> 6, lane = threadIdx.x & 63;
  int j0w = blockIdx.x * 16 + wave * 4;
  const float* crow[4];
  const float* wrow[4];
#pragma unroll
  for (int b = 0; b < 4; ++b) crow[b] = carries + (size_t)(b * CCH + c - 1) * DD;
#pragma unroll
  for (int jj = 0; jj < 4; ++jj) wrow[jj] = W32 + (size_t)(j0w + jj) * DD;
  float acc[4][4];
#pragma unroll
  for (int jj = 0; jj < 4; ++jj)
#pragma unroll
    for (int b = 0; b < 4; ++b) acc[jj][b] = 0.f;
  for (int m = lane; m < DD; m += 64) {
    float w0 = wrow[0][m], w1 = wrow[1][m], w2 = wrow[2][m], w3 = wrow[3][m];
    float c0 = crow[0][m], c1 = crow[1][m], c2 = crow[2][m], c3 = crow[3][m];
    acc[0][0] = fmaf(w0, c0, acc[0][0]); acc[0][1] = fmaf(w0, c1, acc[0][1]);
    acc[0][2] = fmaf(w0, c2, acc[0][2]); acc[0][3] = fmaf(w0, c3, acc[0][3]);
    acc[1][0] = fmaf(w1, c0, acc[1][0]); acc[1][1] = fmaf(w1, c1, acc[1][1]);
    acc[1][2] = fmaf(w1, c2, acc[1][2]); acc[1][3] = fmaf(w1, c3, acc[1][3]);
    acc[2][0] = fmaf(w2, c0, acc[2][0]); acc[2][1] = fmaf(w2, c1, acc[2][1]);
    acc[2][2] = fmaf(w2, c2, acc[2][2]); acc[2][3] = fmaf(w2, c3, acc[2][3]);
    acc[3][0] = fmaf(w3, c0, acc[3][0]); acc[3][1] = fmaf(w3, c1, acc[3][1]);
    acc[3][2] = fmaf(w3, c2, acc[3][2]); acc[3][3] = fmaf(w3, c3, acc[3][3]);
  }
#pragma unroll
  for (int jj = 0; jj < 4; ++jj) {
#pragma unroll
    for (int b = 0; b < 4; ++b) {
      float v = acc[jj][b];
      for (int off = 32; off; off >>= 1) v += __shfl_xor(v, off);
      if (lane == 0) {
        int j = j0w + jj;
        carries[(size_t)(b * CCH + c) * DD + j] =
            v + ends[(size_t)(b * CCH + c - 1) * DD + j];
      }
    }
  }
}

// ---------------- fp32 squaring GEMM: C = A * B (1024^3), 64x64 tile, 4x4/thread ----------------
__global__ __launch_bounds__(256) void k_sq(const float* __restrict__ A,
                                            const float* __restrict__ Bm,
                                            float* __restrict__ Cm) {
  __shared__ float Alt[16][68];  // [k][i] transposed for float4 compute reads
  __shared__ float Bl[16][68];   // [k][j]
  int tid = threadIdx.x;
  int i0 = blockIdx.y * 64, j0 = blockIdx.x * 64;
  int ti = tid >> 4, tj = tid & 15;
  int lrow = tid >> 2, lkq = (tid & 3) * 4;     // A-load mapping
  int lkrow = tid >> 4, ljq = (tid & 15) * 4;   // B-load mapping
  float acc[4][4];
#pragma unroll
  for (int e = 0; e < 4; ++e)
#pragma unroll
    for (int f = 0; f < 4; ++f) acc[e][f] = 0.f;
  for (int k0 = 0; k0 < DD; k0 += 16) {
    float4 av = *(const float4*)(A + (size_t)(i0 + lrow) * DD + k0 + lkq);
    float4 bv = *(const float4*)(Bm + (size_t)(k0 + lkrow) * DD + j0 + ljq);
    __syncthreads();
    Alt[lkq + 0][lrow] = av.x; Alt[lkq + 1][lrow] = av.y;
    Alt[lkq + 2][lrow] = av.z; Alt[lkq + 3][lrow] = av.w;
    *(float4*)&Bl[lkrow][ljq] = bv;
    __syncthreads();
#pragma unroll
    for (int k = 0; k < 16; ++k) {
      float4 a4 = *(const float4*)&Alt[k][ti * 4];
      float4 b4 = *(const float4*)&Bl[k][tj * 4];
      acc[0][0] = fmaf(a4.x, b4.x, acc[0][0]); acc[0][1] = fmaf(a4.x, b4.y, acc[0][1]);
      acc[0][2] = fmaf(a4.x, b4.z, acc[0][2]); acc[0][3] = fmaf(a4.x, b4.w, acc[0][3]);
      acc[1][0] = fmaf(a4.y, b4.x, acc[1][0]); acc[1][1] = fmaf(a4.y, b4.y, acc[1][1]);
      acc[1][2] = fmaf(a4.y, b4.z, acc[1][2]); acc[1][3] = fmaf(a4.y, b4.w, acc[1][3]);
      acc[2][0] = fmaf(a4.z, b4.x, acc[2][0]); acc[2][1] = fmaf(a4.z, b4.y, acc[2][1]);
      acc[2][2] = fmaf(a4.z, b4.z, acc[2][2]); acc[2][3] = fmaf(a4.z, b4.w, acc[2][3]);
      acc[3][0] = fmaf(a4.w, b4.x, acc[3][0]); acc[3][1] = fmaf(a4.w, b4.y, acc[3][1]);
      acc[3][2] = fmaf(a4.w, b4.z, acc[3][2]); acc[3][3] = fmaf(a4.w, b4.w, acc[3][3]);
    }
  }
#pragma unroll
  for (int e = 0; e < 4; ++e) {
    float4 o;
    o.x = acc[e][0]; o.y = acc[e][1]; o.z = acc[e][2]; o.w = acc[e][3];
    *(float4*)(Cm + (size_t)(i0 + ti * 4 + e) * DD + j0 + tj * 4) = o;
  }
}

// ---------------- LM head: bf16 MFMA GEMM, logits = hidden @ lm_w^T + b ----------------
__device__ __forceinline__ void gload16(const void* g, void* l) {
  __builtin_amdgcn_global_load_lds((const __attribute__((address_space(1))) void*)g,
                                   (__attribute__((address_space(3))) void*)l, 16, 0, 0);
}

__global__ __launch_bounds__(256) void k_lmhead(const bf16_t* __restrict__ Ah,
                                                const bf16_t* __restrict__ Bw,
                                                const float* __restrict__ bias,
                                                float* __restrict__ Cout) {
  __shared__ bf16_t Al[128 * 32];
  __shared__ bf16_t Blds[128 * 32];
  int tid = threadIdx.x;
  int wave = tid >> 6, lane = tid & 63;
  int m0 = blockIdx.y * 128, n0 = blockIdx.x * 128;
  int wm = (wave >> 1) * 64, wn = (wave & 1) * 64;
  f32x4_t acc[4][4] = {};
  int frow = lane & 15, fk = (lane >> 4) * 8;

  for (int k0 = 0; k0 < DD; k0 += 32) {
#pragma unroll
    for (int i = 0; i < 2; ++i) {
      int zb = i * 4096 + wave * 1024;       // wave-uniform LDS byte base
      int z = zb + lane * 16;                // this lane's dest byte
      int row = z >> 6, colb = z & 63;
      gload16((const char*)Ah + ((size_t)(m0 + row) * DD + k0) * 2 + colb,
              (char*)Al + zb);
      gload16((const char*)Bw + ((size_t)(n0 + row) * DD + k0) * 2 + colb,
              (char*)Blds + zb);
    }
    __syncthreads();  // drains vmcnt before barrier (compiler-inserted)
    bf16x8_t afr[4], bfr[4];
#pragma unroll
    for (int mf = 0; mf < 4; ++mf)
      afr[mf] = *(const bf16x8_t*)&Al[(wm + mf * 16 + frow) * 32 + fk];
#pragma unroll
    for (int nf = 0; nf < 4; ++nf)
      bfr[nf] = *(const bf16x8_t*)&Blds[(wn + nf * 16 + frow) * 32 + fk];
#pragma unroll
    for (int mf = 0; mf < 4; ++mf)
#pragma unroll
      for (int nf = 0; nf < 4; ++nf)
        acc[mf][nf] = __builtin_amdgcn_mfma_f32_16x16x32_bf16(afr[mf], bfr[nf],
                                                              acc[mf][nf], 0, 0, 0);
    __syncthreads();  // all reads done before next stage overwrites
  }
  // C/D layout: col = lane&15, row = (lane>>4)*4 + reg  [m89-verified]
  int ecol = lane & 15, erow4 = (lane >> 4) * 4;
#pragma unroll
  for (int mf = 0; mf < 4; ++mf) {
#pragma unroll
    for (int nf = 0; nf < 4; ++nf) {
      int gm = m0 + wm + mf * 16 + erow4;
      int gn = n0 + wn + nf * 16 + ecol;
      float bv = bias[gn];
#pragma unroll
      for (int reg = 0; reg < 4; ++reg)
        Cout[(size_t)(gm + reg) * VV + gn] = acc[mf][nf][reg] + bv;
    }
  }
}

// ---------------- host orchestration ----------------
extern "C" void kernel_launch(void* const* d_in, const int* in_sizes, int n_in,
                              void* d_out, int out_size, void* d_ws, size_t ws_size,
                              hipStream_t stream) {
  (void)in_sizes; (void)n_in; (void)out_size;
  const int* ids = (const int*)d_in[0];
  const float* embed = (const float*)d_in[1];
  const float* w_state = (const float*)d_in[2];
  const float* lm_w = (const float*)d_in[3];
  const float* lm_b = (const float*)d_in[4];
  float* out = (float*)d_out;

  // workspace carve (~58.3 MB)
  float* Wa = (float*)d_ws;                 // 1024x1024
  float* Wb = Wa + 1024 * 1024;             // 1024x1024
  float* S0 = Wb + 1024 * 1024;             // 256x1024
  float* S1 = S0 + NR * DD;                 // 256x1024
  float* CAR = S1 + NR * DD;                // 256x1024
  bf16_t* HID = (bf16_t*)(CAR + NR * DD);   // 8192x1024 bf16
  bf16_t* LWB = HID + (size_t)BB * TT * DD; // 16000x1024 bf16
  (void)ws_size;

  // 1. lm_w -> bf16
  k_cvt<<<2048, 256, 0, stream>>>(lm_w, LWB, VV * DD / 4);

  // 2. W^32 by repeated squaring (fp32 — precision-mandatory)
  dim3 gsq(16, 16);
  k_sq<<<gsq, 256, 0, stream>>>(w_state, w_state, Wa);  // W^2
  k_sq<<<gsq, 256, 0, stream>>>(Wa, Wa, Wb);            // W^4
  k_sq<<<gsq, 256, 0, stream>>>(Wb, Wb, Wa);            // W^8
  k_sq<<<gsq, 256, 0, stream>>>(Wa, Wa, Wb);            // W^16
  k_sq<<<gsq, 256, 0, stream>>>(Wb, Wb, Wa);            // W^32

  // 3. phase A: chunk-local zero-init scans (lockstep rounds)
  k_gather0<<<256, 256, 0, stream>>>(embed, ids, S0);
  dim3 gr(32, 8);
  const float* pin = S0;
  for (int d = 1; d < LCH; ++d) {
    float* pout = (d & 1) ? S1 : S0;
    k_round<false><<<gr, 256, 0, stream>>>(pin, pout, w_state, embed, ids, d, nullptr);
    pin = pout;
  }
  const float* ENDS = pin;  // = S1 (d=31 odd)

  // 4. carry chain across chunks with W^32
  hipMemsetAsync(CAR, 0, (size_t)NR * DD * sizeof(float), stream);
  for (int c = 1; c < CCH; ++c)
    k_carry<<<64, 256, 0, stream>>>(CAR, ENDS, Wa, c);

  // 5. phase C: final scan from correct carries, emit hidden (bf16)
  for (int d = 0; d < LCH; ++d) {
    const float* pi = (d == 0) ? CAR : ((d & 1) ? S0 : S1);
    float* po = (d & 1) ? S1 : S0;
    k_round<true><<<gr, 256, 0, stream>>>(pi, po, w_state, embed, ids, d, HID);
  }

  // 6. LM head (bf16 MFMA) + bias -> fp32 logits
  dim3 gl(VV / 128, (BB * TT) / 128);
  k_lmhead<<<gl, 256, 0, stream>>>(HID, LWB, lm_b, out);
}

// Round 2
// 1920.129 us; speedup vs baseline: 3.1239x; 3.1239x over previous
//
#include <hip/hip_runtime.h>
#include <hip/hip_bf16.h>
#include <stdint.h>

#define DD 1024   // hidden dim
#define BB 4      // batch
#define TT 2048   // seq len
#define VV 16000  // vocab
#define LCH 8     // chunk length
#define CCH 256   // num chunks
#define NR 1024   // BB*CCH rows, r = c*4 + b
#define PAD_ROWS 512

typedef __bf16 bf16_t;
typedef float f32x4_t __attribute__((ext_vector_type(4)));
typedef bf16_t bf16x8_t __attribute__((ext_vector_type(8)));

#define MODE_PLAIN 0
#define MODE_ROUND 1
#define MODE_LEVEL 2
#define MODE_CARRY 3

// ---------------- fp32 -> bf16 convert (lm_w) ----------------
__global__ __launch_bounds__(256) void k_cvt(const float* __restrict__ src,
                                             bf16_t* __restrict__ dst, int n4) {
  int i = blockIdx.x * blockDim.x + threadIdx.x;
  int stride = gridDim.x * blockDim.x;
  for (; i < n4; i += stride) {
    float4 v = ((const float4*)src)[i];
    union { ushort4 u; bf16_t h[4]; } p;
    p.h[0] = (bf16_t)v.x; p.h[1] = (bf16_t)v.y;
    p.h[2] = (bf16_t)v.z; p.h[3] = (bf16_t)v.w;
    ((ushort4*)dst)[i] = p.u;
  }
}

// ---------------- 1024x1024 fp32 transpose ----------------
__global__ __launch_bounds__(256) void k_tr(const float* __restrict__ in,
                                            float* __restrict__ out) {
  __shared__ float t[32][33];
  int bx = blockIdx.x * 32, by = blockIdx.y * 32;
  int tx = threadIdx.x & 31, ty = threadIdx.x >> 5;  // 32 x 8
#pragma unroll
  for (int q = 0; q < 4; ++q)
    t[ty + q * 8][tx] = in[(size_t)(by + ty + q * 8) * DD + bx + tx];
  __syncthreads();
#pragma unroll
  for (int q = 0; q < 4; ++q)
    out[(size_t)(bx + ty + q * 8) * DD + by + tx] = t[tx][ty + q * 8];
}

// ---------------- gather chunk-start rows into locals slab 0 ----------------
__global__ __launch_bounds__(256) void k_gather(const float* __restrict__ embed,
                                                const int* __restrict__ ids,
                                                float* __restrict__ slab0) {
  int r = blockIdx.x;  // 0..1023
  int b = r & 3, c = r >> 2;
  int id = ids[b * TT + c * LCH];
  const float4* s = (const float4*)(embed + (size_t)id * DD);
  float4* d = (float4*)(slab0 + (size_t)r * DD);
  for (int i = threadIdx.x; i < DD / 4; i += blockDim.x) d[i] = s[i];
}

// ---------------- general NT fp32 GEMM: C = A @ B_stored^T (+ mode epilogue) ----------------
// 64x64 tile, BK=16, 4x4/thread, LDS-transposed operands, global prefetch.
template <int MODE>
__global__ __launch_bounds__(256, 2) void k_gemm(
    const float* __restrict__ A, const float* __restrict__ Bm,
    float* __restrict__ Cout, const float* __restrict__ Cin,
    const float* __restrict__ embed, const int* __restrict__ ids, int dlt,
    const float* __restrict__ locals, bf16_t* __restrict__ hidden) {
  __shared__ float Asub[16][68];
  __shared__ float Bsub[16][68];
  int tid = threadIdx.x;
  int i0 = blockIdx.y * 64, j0 = blockIdx.x * 64;
  int z = 0;
  if (MODE == MODE_CARRY) {
    z = blockIdx.z;
    Bm += (size_t)z * DD * DD;      // B = W^{z+1}
    locals += (size_t)z * NR * DD;  // locals slab z
  }
  int lrow = tid >> 2, lkq = (tid & 3) * 4;  // load mapping
  int ti = tid >> 4, tj = tid & 15;          // compute mapping
  const float* Arow = A + (size_t)(i0 + lrow) * DD + lkq;
  const float* Brow = Bm + (size_t)(j0 + lrow) * DD + lkq;
  float4 av = *(const float4*)(Arow);
  float4 bv = *(const float4*)(Brow);
  float acc[4][4];
#pragma unroll
  for (int e = 0; e < 4; ++e)
#pragma unroll
    for (int f = 0; f < 4; ++f) acc[e][f] = 0.f;

  for (int k0 = 0; k0 < DD; k0 += 16) {
    __syncthreads();
    Asub[lkq + 0][lrow] = av.x; Asub[lkq + 1][lrow] = av.y;
    Asub[lkq + 2][lrow] = av.z; Asub[lkq + 3][lrow] = av.w;
    Bsub[lkq + 0][lrow] = bv.x; Bsub[lkq + 1][lrow] = bv.y;
    Bsub[lkq + 2][lrow] = bv.z; Bsub[lkq + 3][lrow] = bv.w;
    __syncthreads();
    if (k0 + 16 < DD) {  // prefetch next K-tile; latency hides under compute
      av = *(const float4*)(Arow + k0 + 16);
      bv = *(const float4*)(Brow + k0 + 16);
    }
#pragma unroll
    for (int k = 0; k < 16; ++k) {
      float4 a4 = *(const float4*)&Asub[k][ti * 4];
      float4 b4 = *(const float4*)&Bsub[k][tj * 4];
      acc[0][0] = fmaf(a4.x, b4.x, acc[0][0]); acc[0][1] = fmaf(a4.x, b4.y, acc[0][1]);
      acc[0][2] = fmaf(a4.x, b4.z, acc[0][2]); acc[0][3] = fmaf(a4.x, b4.w, acc[0][3]);
      acc[1][0] = fmaf(a4.y, b4.x, acc[1][0]); acc[1][1] = fmaf(a4.y, b4.y, acc[1][1]);
      acc[1][2] = fmaf(a4.y, b4.z, acc[1][2]); acc[1][3] = fmaf(a4.y, b4.w, acc[1][3]);
      acc[2][0] = fmaf(a4.z, b4.x, acc[2][0]); acc[2][1] = fmaf(a4.z, b4.y, acc[2][1]);
      acc[2][2] = fmaf(a4.z, b4.z, acc[2][2]); acc[2][3] = fmaf(a4.z, b4.w, acc[2][3]);
      acc[3][0] = fmaf(a4.w, b4.x, acc[3][0]); acc[3][1] = fmaf(a4.w, b4.y, acc[3][1]);
      acc[3][2] = fmaf(a4.w, b4.z, acc[3][2]); acc[3][3] = fmaf(a4.w, b4.w, acc[3][3]);
    }
  }

  // epilogue
#pragma unroll
  for (int e = 0; e < 4; ++e) {
    int ri = i0 + ti * 4 + e;
    int col = j0 + tj * 4;
    if (MODE == MODE_PLAIN) {
      float4 o; o.x = acc[e][0]; o.y = acc[e][1]; o.z = acc[e][2]; o.w = acc[e][3];
      *(float4*)(Cout + (size_t)ri * DD + col) = o;
    } else if (MODE == MODE_ROUND) {
      int b = ri & 3, c = ri >> 2;
      int t = c * LCH + dlt;
      int id = ids[b * TT + t];
      float4 em = *(const float4*)(embed + (size_t)id * DD + col);
      float4 o;
      o.x = acc[e][0] + em.x; o.y = acc[e][1] + em.y;
      o.z = acc[e][2] + em.z; o.w = acc[e][3] + em.w;
      *(float4*)(Cout + (size_t)ri * DD + col) = o;
    } else if (MODE == MODE_LEVEL) {
      float4 ci = *(const float4*)(Cin + (size_t)ri * DD + col);
      float4 o;
      o.x = acc[e][0] + ci.x; o.y = acc[e][1] + ci.y;
      o.z = acc[e][2] + ci.z; o.w = acc[e][3] + ci.w;
      *(float4*)(Cout + (size_t)ri * DD + col) = o;
    } else {  // MODE_CARRY: hidden = locals + carry-transform, bf16 out
      int b = ri & 3, c = ri >> 2;
      int t = c * LCH + z;
      float4 lc = *(const float4*)(locals + (size_t)ri * DD + col);
      union { ushort4 u; bf16_t h[4]; } p;
      p.h[0] = (bf16_t)(acc[e][0] + lc.x);
      p.h[1] = (bf16_t)(acc[e][1] + lc.y);
      p.h[2] = (bf16_t)(acc[e][2] + lc.z);
      p.h[3] = (bf16_t)(acc[e][3] + lc.w);
      *(ushort4*)(hidden + ((size_t)b * TT + t) * DD + col) = p.u;
    }
  }
}

// ---------------- LM head: bf16 MFMA GEMM, logits = hidden @ lm_w^T + b ----------------
__device__ __forceinline__ void gload16(const void* g, void* l) {
  __builtin_amdgcn_global_load_lds((const __attribute__((address_space(1))) void*)g,
                                   (__attribute__((address_space(3))) void*)l, 16, 0, 0);
}

__global__ __launch_bounds__(256) void k_lmhead(const bf16_t* __restrict__ Ah,
                                                const bf16_t* __restrict__ Bw,
                                                const float* __restrict__ bias,
                                                float* __restrict__ Cout) {
  __shared__ bf16_t Al[128 * 32];
  __shared__ bf16_t Blds[128 * 32];
  int tid = threadIdx.x;
  int wave = tid >> 6, lane = tid & 63;
  int m0 = blockIdx.y * 128, n0 = blockIdx.x * 128;
  int wm = (wave >> 1) * 64, wn = (wave & 1) * 64;
  f32x4_t acc[4][4] = {};
  int frow = lane & 15, fk = (lane >> 4) * 8;

  for (int k0 = 0; k0 < DD; k0 += 32) {
#pragma unroll
    for (int i = 0; i < 2; ++i) {
      int zb = i * 4096 + wave * 1024;
      int zz = zb + lane * 16;
      int row = zz >> 6, colb = zz & 63;
      gload16((const char*)Ah + ((size_t)(m0 + row) * DD + k0) * 2 + colb,
              (char*)Al + zb);
      gload16((const char*)Bw + ((size_t)(n0 + row) * DD + k0) * 2 + colb,
              (char*)Blds + zb);
    }
    __syncthreads();
    bf16x8_t afr[4], bfr[4];
#pragma unroll
    for (int mf = 0; mf < 4; ++mf)
      afr[mf] = *(const bf16x8_t*)&Al[(wm + mf * 16 + frow) * 32 + fk];
#pragma unroll
    for (int nf = 0; nf < 4; ++nf)
      bfr[nf] = *(const bf16x8_t*)&Blds[(wn + nf * 16 + frow) * 32 + fk];
#pragma unroll
    for (int mf = 0; mf < 4; ++mf)
#pragma unroll
      for (int nf = 0; nf < 4; ++nf)
        acc[mf][nf] = __builtin_amdgcn_mfma_f32_16x16x32_bf16(afr[mf], bfr[nf],
                                                              acc[mf][nf], 0, 0, 0);
    __syncthreads();
  }
  int ecol = lane & 15, erow4 = (lane >> 4) * 4;
#pragma unroll
  for (int mf = 0; mf < 4; ++mf) {
#pragma unroll
    for (int nf = 0; nf < 4; ++nf) {
      int gm = m0 + wm + mf * 16 + erow4;
      int gn = n0 + wn + nf * 16 + ecol;
      float bv = bias[gn];
#pragma unroll
      for (int reg = 0; reg < 4; ++reg)
        Cout[(size_t)(gm + reg) * VV + gn] = acc[mf][nf][reg] + bv;
    }
  }
}

// ---------------- host orchestration ----------------
extern "C" void kernel_launch(void* const* d_in, const int* in_sizes, int n_in,
                              void* d_out, int out_size, void* d_ws, size_t ws_size,
                              hipStream_t stream) {
  (void)in_sizes; (void)n_in; (void)out_size; (void)ws_size;
  const int* ids = (const int*)d_in[0];
  const float* embed = (const float*)d_in[1];
  const float* w_state = (const float*)d_in[2];
  const float* lm_w = (const float*)d_in[3];
  const float* lm_b = (const float*)d_in[4];
  float* out = (float*)d_out;

  const size_t M1 = (size_t)DD * DD;  // 1M floats
  float* Wt = (float*)d_ws;                 // 1M   W^T
  float* P = Wt + M1;                       // 8M   W^1..W^8
  float* LOC = P + 8 * M1;                  // 8M   locals slabs d=0..7
  float* E0 = LOC + 8 * M1;                 // 1.5M (512-row zero pad + 1024 rows)
  float* E1 = E0 + (PAD_ROWS + NR) * DD;    // 1.5M
  float* QA = E1 + (PAD_ROWS + NR) * DD;    // 1M
  float* QB = QA + M1;                      // 1M
  float* TQ = QB + M1;                      // 1M
  bf16_t* HID = (bf16_t*)(TQ + M1);         // 8M bf16
  bf16_t* LWB = HID + (size_t)BB * TT * DD; // 16.4M bf16
  float* E0d = E0 + (size_t)PAD_ROWS * DD;
  float* E1d = E1 + (size_t)PAD_ROWS * DD;

  dim3 g64(16, 16);  // 1024x1024 output in 64x64 tiles

  // 1. lm_w -> bf16
  k_cvt<<<2048, 256, 0, stream>>>(lm_w, LWB, VV * DD / 4);

  // 2. W^T, P[0] = W
  k_tr<<<dim3(32, 32), 256, 0, stream>>>(w_state, Wt);
  hipMemcpyAsync(P, w_state, M1 * sizeof(float), hipMemcpyDeviceToDevice, stream);

  // 3. P-chain: P[n] = W^{n+1} = P[n-1] @ (Wt)^T
  for (int n = 1; n < LCH; ++n)
    k_gemm<MODE_PLAIN><<<g64, 256, 0, stream>>>(P + (size_t)(n - 1) * M1, Wt,
                                                P + (size_t)n * M1, nullptr,
                                                nullptr, nullptr, 0, nullptr, nullptr);

  // 4. phase A: locals slabs (7 sequential rounds), B = W (NT -> @W^T)
  k_gather<<<NR, 256, 0, stream>>>(embed, ids, LOC);
  for (int d = 1; d < LCH; ++d)
    k_gemm<MODE_ROUND><<<g64, 256, 0, stream>>>(LOC + (size_t)(d - 1) * NR * DD, w_state,
                                                LOC + (size_t)d * NR * DD, nullptr,
                                                embed, ids, d, nullptr, nullptr);

  // 5. chunk-end scan init: E0 = [zeros(512) | locals slab 7]
  hipMemsetAsync(E0, 0, (size_t)PAD_ROWS * DD * sizeof(float), stream);
  hipMemsetAsync(E1, 0, (size_t)PAD_ROWS * DD * sizeof(float), stream);
  hipMemcpyAsync(E0d, LOC + (size_t)(LCH - 1) * NR * DD, (size_t)NR * DD * sizeof(float),
                 hipMemcpyDeviceToDevice, stream);

  // 6. Hillis-Steele over 256 chunks: 8 levels, Q_k = W^{8*2^k}
  const float* Qk = P + (size_t)(LCH - 1) * M1;  // W^8
  float* inp = E0d;
  float* outp = E1d;
  for (int k = 0; k < 8; ++k) {
    if (k > 0) {
      k_tr<<<dim3(32, 32), 256, 0, stream>>>(Qk, TQ);
      float* Qn = (k & 1) ? QA : QB;
      k_gemm<MODE_PLAIN><<<g64, 256, 0, stream>>>(Qk, TQ, Qn, nullptr,
                                                  nullptr, nullptr, 0, nullptr, nullptr);
      Qk = Qn;
    }
    k_gemm<MODE_LEVEL><<<g64, 256, 0, stream>>>(inp - (size_t)(4 << k) * DD, Qk,
                                                outp, inp,
                                                nullptr, nullptr, 0, nullptr, nullptr);
    float* tmp = inp; inp = outp; outp = tmp;
  }
  // after 8 levels result is back in E0d (inp)

  // 7. batched carry-apply: hidden[b][c*8+d] = locals[d][r] + E_{c-1} @ (W^{d+1})^T
  dim3 gc(16, 16, LCH);
  k_gemm<MODE_CARRY><<<gc, 256, 0, stream>>>(inp - (size_t)4 * DD, P,
                                             nullptr, nullptr,
                                             nullptr, nullptr, 0, LOC, HID);

  // 8. LM head
  dim3 gl(VV / 128, (BB * TT) / 128);
  k_lmhead<<<gl, 256, 0, stream>>>(HID, LWB, lm_b, out);
}

// Round 3
// 1729.431 us; speedup vs baseline: 3.4684x; 1.1103x over previous
//
#include <hip/hip_runtime.h>
#include <hip/hip_bf16.h>
#include <stdint.h>

#define DD 1024   // hidden dim
#define BB 4      // batch
#define TT 2048   // seq len
#define VV 16000  // vocab
#define LCH 8     // chunk length
#define CCH 256   // num chunks
#define NR 1024   // BB*CCH rows, r = c*4 + b
#define PAD_ROWS 512

typedef __bf16 bf16_t;
typedef float f32x4_t __attribute__((ext_vector_type(4)));
typedef bf16_t bf16x8_t __attribute__((ext_vector_type(8)));

#define MODE_PLAIN 0
#define MODE_ROUND 1
#define MODE_LEVEL 2
#define MODE_CARRY 3

// ---------------- fp32 -> bf16 convert (lm_w) ----------------
__global__ __launch_bounds__(256) void k_cvt(const float* __restrict__ src,
                                             bf16_t* __restrict__ dst, int n4) {
  int i = blockIdx.x * blockDim.x + threadIdx.x;
  int stride = gridDim.x * blockDim.x;
  for (; i < n4; i += stride) {
    float4 v = ((const float4*)src)[i];
    union { ushort4 u; bf16_t h[4]; } p;
    p.h[0] = (bf16_t)v.x; p.h[1] = (bf16_t)v.y;
    p.h[2] = (bf16_t)v.z; p.h[3] = (bf16_t)v.w;
    ((ushort4*)dst)[i] = p.u;
  }
}

// ---------------- gather chunk-start rows into locals slab 0 ----------------
__global__ __launch_bounds__(256) void k_gather(const float* __restrict__ embed,
                                                const int* __restrict__ ids,
                                                float* __restrict__ slab0) {
  int r = blockIdx.x;  // 0..1023
  int b = r & 3, c = r >> 2;
  int id = ids[b * TT + c * LCH];
  const float4* s = (const float4*)(embed + (size_t)id * DD);
  float4* d = (float4*)(slab0 + (size_t)r * DD);
  for (int i = threadIdx.x; i < DD / 4; i += blockDim.x) d[i] = s[i];
}

// ---------------- fp32 GEMM body: C = A@B^T (NT) or A@B (NN), mode epilogue ----
// 64x64 tile, BK=16, 4x4/thread, LDS-transposed A, global prefetch.
template <int MODE, bool NN>
__device__ __forceinline__ void gemm_body(
    float (*Asub)[68], float (*Bsub)[68],
    const float* __restrict__ A, const float* __restrict__ Bm,
    float* __restrict__ Cout, const float* __restrict__ Cin,
    const float* __restrict__ embed, const int* __restrict__ ids, int dlt,
    const float* __restrict__ locals, bf16_t* __restrict__ hidden, int z) {
  int tid = threadIdx.x;
  int i0 = blockIdx.y * 64, j0 = blockIdx.x * 64;
  if (MODE == MODE_CARRY) {
    Bm += (size_t)z * DD * DD;      // B = W^{z+1}
    locals += (size_t)z * NR * DD;  // locals slab z
  }
  int lrow = tid >> 2, lkq = (tid & 3) * 4;   // NT load mapping
  int lkrow = tid >> 4, ljq = (tid & 15) * 4; // NN B load mapping
  int ti = tid >> 4, tj = tid & 15;           // compute mapping
  const float* Arow = A + (size_t)(i0 + lrow) * DD + lkq;
  const float* Brow;
  if (NN) Brow = Bm + (size_t)lkrow * DD + j0 + ljq;
  else    Brow = Bm + (size_t)(j0 + lrow) * DD + lkq;
  float4 av = *(const float4*)(Arow);
  float4 bv = *(const float4*)(Brow);
  float acc[4][4];
#pragma unroll
  for (int e = 0; e < 4; ++e)
#pragma unroll
    for (int f = 0; f < 4; ++f) acc[e][f] = 0.f;

  for (int k0 = 0; k0 < DD; k0 += 16) {
    __syncthreads();
    Asub[lkq + 0][lrow] = av.x; Asub[lkq + 1][lrow] = av.y;
    Asub[lkq + 2][lrow] = av.z; Asub[lkq + 3][lrow] = av.w;
    if (NN) {
      *(float4*)&Bsub[lkrow][ljq] = bv;
    } else {
      Bsub[lkq + 0][lrow] = bv.x; Bsub[lkq + 1][lrow] = bv.y;
      Bsub[lkq + 2][lrow] = bv.z; Bsub[lkq + 3][lrow] = bv.w;
    }
    __syncthreads();
    if (k0 + 16 < DD) {  // prefetch next K-tile; latency hides under compute
      av = *(const float4*)(Arow + k0 + 16);
      bv = NN ? *(const float4*)(Brow + (size_t)(k0 + 16) * DD)
              : *(const float4*)(Brow + k0 + 16);
    }
#pragma unroll
    for (int k = 0; k < 16; ++k) {
      float4 a4 = *(const float4*)&Asub[k][ti * 4];
      float4 b4 = *(const float4*)&Bsub[k][tj * 4];
      acc[0][0] = fmaf(a4.x, b4.x, acc[0][0]); acc[0][1] = fmaf(a4.x, b4.y, acc[0][1]);
      acc[0][2] = fmaf(a4.x, b4.z, acc[0][2]); acc[0][3] = fmaf(a4.x, b4.w, acc[0][3]);
      acc[1][0] = fmaf(a4.y, b4.x, acc[1][0]); acc[1][1] = fmaf(a4.y, b4.y, acc[1][1]);
      acc[1][2] = fmaf(a4.y, b4.z, acc[1][2]); acc[1][3] = fmaf(a4.y, b4.w, acc[1][3]);
      acc[2][0] = fmaf(a4.z, b4.x, acc[2][0]); acc[2][1] = fmaf(a4.z, b4.y, acc[2][1]);
      acc[2][2] = fmaf(a4.z, b4.z, acc[2][2]); acc[2][3] = fmaf(a4.z, b4.w, acc[2][3]);
      acc[3][0] = fmaf(a4.w, b4.x, acc[3][0]); acc[3][1] = fmaf(a4.w, b4.y, acc[3][1]);
      acc[3][2] = fmaf(a4.w, b4.z, acc[3][2]); acc[3][3] = fmaf(a4.w, b4.w, acc[3][3]);
    }
  }

  // epilogue
#pragma unroll
  for (int e = 0; e < 4; ++e) {
    int ri = i0 + ti * 4 + e;
    int col = j0 + tj * 4;
    if (MODE == MODE_PLAIN) {
      float4 o; o.x = acc[e][0]; o.y = acc[e][1]; o.z = acc[e][2]; o.w = acc[e][3];
      *(float4*)(Cout + (size_t)ri * DD + col) = o;
    } else if (MODE == MODE_ROUND) {
      int b = ri & 3, c = ri >> 2;
      int t = c * LCH + dlt;
      int id = ids[b * TT + t];
      float4 em = *(const float4*)(embed + (size_t)id * DD + col);
      float4 o;
      o.x = acc[e][0] + em.x; o.y = acc[e][1] + em.y;
      o.z = acc[e][2] + em.z; o.w = acc[e][3] + em.w;
      *(float4*)(Cout + (size_t)ri * DD + col) = o;
    } else if (MODE == MODE_LEVEL) {
      float4 ci = *(const float4*)(Cin + (size_t)ri * DD + col);
      float4 o;
      o.x = acc[e][0] + ci.x; o.y = acc[e][1] + ci.y;
      o.z = acc[e][2] + ci.z; o.w = acc[e][3] + ci.w;
      *(float4*)(Cout + (size_t)ri * DD + col) = o;
    } else {  // MODE_CARRY: hidden = locals + carry-transform, bf16 out
      int b = ri & 3, c = ri >> 2;
      int t = c * LCH + z;
      float4 lc = *(const float4*)(locals + (size_t)ri * DD + col);
      union { ushort4 u; bf16_t h[4]; } p;
      p.h[0] = (bf16_t)(acc[e][0] + lc.x);
      p.h[1] = (bf16_t)(acc[e][1] + lc.y);
      p.h[2] = (bf16_t)(acc[e][2] + lc.z);
      p.h[3] = (bf16_t)(acc[e][3] + lc.w);
      *(ushort4*)(hidden + ((size_t)b * TT + t) * DD + col) = p.u;
    }
  }
}

// single-GEMM launcher (grid z used for CARRY batch)
template <int MODE, bool NN>
__global__ __launch_bounds__(256, 2) void k_one(
    const float* __restrict__ A, const float* __restrict__ Bm,
    float* __restrict__ Cout, const float* __restrict__ Cin,
    const float* __restrict__ embed, const int* __restrict__ ids, int dlt,
    const float* __restrict__ locals, bf16_t* __restrict__ hidden) {
  __shared__ float Asub[16][68];
  __shared__ float Bsub[16][68];
  gemm_body<MODE, NN>(Asub, Bsub, A, Bm, Cout, Cin, embed, ids, dlt,
                      locals, hidden, blockIdx.z);
}

// dual-GEMM launcher: z=0 -> (M0,NN0) on set-0 args, z=1 -> (M1,NN1) on set-1
template <int M0, bool NN0, int M1, bool NN1>
__global__ __launch_bounds__(256, 2) void k_dual(
    const float* __restrict__ A0, const float* __restrict__ B0,
    float* __restrict__ C0,
    const float* __restrict__ A1, const float* __restrict__ B1,
    float* __restrict__ C1, const float* __restrict__ Cin1,
    const float* __restrict__ embed, const int* __restrict__ ids, int dlt) {
  __shared__ float Asub[16][68];
  __shared__ float Bsub[16][68];
  if (blockIdx.z == 0)
    gemm_body<M0, NN0>(Asub, Bsub, A0, B0, C0, nullptr, embed, ids, dlt,
                       nullptr, nullptr, 0);
  else
    gemm_body<M1, NN1>(Asub, Bsub, A1, B1, C1, Cin1, embed, ids, dlt,
                       nullptr, nullptr, 0);
}

// ---------------- LM head: bf16 MFMA GEMM, logits = hidden @ lm_w^T + b ------
// BK=64, [128][64] bf16 LDS tiles, XOR-swizzle (row&7)<<4 via pre-swizzled
// global source (rule #21: linear gload_lds dest + inv-swz source + swz read).
__device__ __forceinline__ void gload16(const void* g, void* l) {
  __builtin_amdgcn_global_load_lds((const __attribute__((address_space(1))) void*)g,
                                   (__attribute__((address_space(3))) void*)l, 16, 0, 0);
}

__global__ __launch_bounds__(256) void k_lmhead(const bf16_t* __restrict__ Ah,
                                                const bf16_t* __restrict__ Bw,
                                                const float* __restrict__ bias,
                                                float* __restrict__ Cout) {
  __shared__ bf16_t Al[128 * 64];
  __shared__ bf16_t Bl[128 * 64];
  // XCD-aware swizzle: nwg = 125*64 = 8000, 8000 % 8 == 0 -> simple form
  int orig = blockIdx.y * gridDim.x + blockIdx.x;
  int swz = (orig & 7) * 1000 + (orig >> 3);
  int bx = swz % 125, by = swz / 125;
  int m0 = by * 128, n0 = bx * 128;
  int tid = threadIdx.x;
  int wave = tid >> 6, lane = tid & 63;
  int wm = (wave >> 1) * 64, wn = (wave & 1) * 64;
  f32x4_t acc[4][4] = {};
  int frow = lane & 15;

  for (int k0 = 0; k0 < DD; k0 += 64) {
#pragma unroll
    for (int it = 0; it < 4; ++it) {
      int zb = it * 4096 + wave * 1024;   // wave-uniform LDS byte base
      int tpos = zb + lane * 16;          // linear dest byte of this lane
      int row = tpos >> 7;                // 128B rows
      int scol = (tpos & 127) ^ ((row & 7) << 4);  // inverse-swizzled source
      gload16((const char*)Ah + ((size_t)(m0 + row) * DD + k0) * 2 + scol,
              (char*)Al + zb);
      gload16((const char*)Bw + ((size_t)(n0 + row) * DD + k0) * 2 + scol,
              (char*)Bl + zb);
    }
    __syncthreads();  // vmcnt drained by compiler before barrier
    bf16x8_t afr[2][4], bfr[2][4];
#pragma unroll
    for (int b = 0; b < 2; ++b) {
#pragma unroll
      for (int mf = 0; mf < 4; ++mf) {
        int r = wm + mf * 16 + frow;          // (r&7) == (frow&7), same for B
        int off = (b * 64 + (lane >> 4) * 16) ^ ((r & 7) << 4);
        afr[b][mf] = *(const bf16x8_t*)((const char*)Al + r * 128 + off);
        int rn = wn + mf * 16 + frow;
        bfr[b][mf] = *(const bf16x8_t*)((const char*)Bl + rn * 128 + off);
      }
    }
#pragma unroll
    for (int b = 0; b < 2; ++b)
#pragma unroll
      for (int mf = 0; mf < 4; ++mf)
#pragma unroll
        for (int nf = 0; nf < 4; ++nf)
          acc[mf][nf] = __builtin_amdgcn_mfma_f32_16x16x32_bf16(
              afr[b][mf], bfr[b][nf], acc[mf][nf], 0, 0, 0);
    __syncthreads();
  }
  // C/D layout: col = lane&15, row = (lane>>4)*4 + reg  [m89-verified]
  int ecol = lane & 15, erow4 = (lane >> 4) * 4;
#pragma unroll
  for (int mf = 0; mf < 4; ++mf) {
#pragma unroll
    for (int nf = 0; nf < 4; ++nf) {
      int gm = m0 + wm + mf * 16 + erow4;
      int gn = n0 + wn + nf * 16 + ecol;
      float bv = bias[gn];
#pragma unroll
      for (int reg = 0; reg < 4; ++reg)
        Cout[(size_t)(gm + reg) * VV + gn] = acc[mf][nf][reg] + bv;
    }
  }
}

// ---------------- host orchestration ----------------
extern "C" void kernel_launch(void* const* d_in, const int* in_sizes, int n_in,
                              void* d_out, int out_size, void* d_ws, size_t ws_size,
                              hipStream_t stream) {
  (void)in_sizes; (void)n_in; (void)out_size; (void)ws_size;
  const int* ids = (const int*)d_in[0];
  const float* embed = (const float*)d_in[1];
  const float* w_state = (const float*)d_in[2];
  const float* lm_w = (const float*)d_in[3];
  const float* lm_b = (const float*)d_in[4];
  float* out = (float*)d_out;

  const size_t M1 = (size_t)DD * DD;  // 1M floats
  float* P = (float*)d_ws;                  // 8M   W^1..W^8
  float* LOC = P + 8 * M1;                  // 8M   locals slabs d=0..7
  float* E0 = LOC + 8 * M1;                 // 1.5M (512-row zero pad + 1024 rows)
  float* E1 = E0 + (PAD_ROWS + NR) * DD;    // 1.5M
  float* QA = E1 + (PAD_ROWS + NR) * DD;    // 1M
  float* QB = QA + M1;                      // 1M
  bf16_t* HID = (bf16_t*)(QB + M1);         // 8M bf16
  bf16_t* LWB = HID + (size_t)BB * TT * DD; // 16.4M bf16
  float* E0d = E0 + (size_t)PAD_ROWS * DD;
  float* E1d = E1 + (size_t)PAD_ROWS * DD;

  // 1. lm_w -> bf16 ; P[0] = W ; gather locals slab 0 ; pad zeroing
  k_cvt<<<2048, 256, 0, stream>>>(lm_w, LWB, VV * DD / 4);
  hipMemcpyAsync(P, w_state, M1 * sizeof(float), hipMemcpyDeviceToDevice, stream);
  k_gather<<<NR, 256, 0, stream>>>(embed, ids, LOC);
  hipMemsetAsync(E0, 0, (size_t)PAD_ROWS * DD * sizeof(float), stream);
  hipMemsetAsync(E1, 0, (size_t)PAD_ROWS * DD * sizeof(float), stream);

  // 2. fused steps 1..7: z0: P[n] = P[n-1] (NN) W ; z1: LOC[d] = LOC[d-1] @ W^T + h_d
  dim3 gd(16, 16, 2);
  for (int n = 1; n < LCH; ++n)
    k_dual<MODE_PLAIN, true, MODE_ROUND, false><<<gd, 256, 0, stream>>>(
        P + (size_t)(n - 1) * M1, w_state, P + (size_t)n * M1,
        LOC + (size_t)(n - 1) * NR * DD, w_state, LOC + (size_t)n * NR * DD,
        nullptr, embed, ids, n);

  // 3. E0 = locals slab 7 (chunk ends)
  hipMemcpyAsync(E0d, LOC + (size_t)(LCH - 1) * NR * DD,
                 (size_t)NR * DD * sizeof(float), hipMemcpyDeviceToDevice, stream);

  // 4. fused steps 8..14 (k=0..6): z0: Q_{k+1} = Q_k (NN) Q_k ; z1: level_k
  //    Q_0 = P[7] = W^8; Q_{k+1} dest alternates QA/QB.
  float* inp = E0d;
  float* outp = E1d;
  for (int k = 0; k < 7; ++k) {
    const float* Qk = (k == 0) ? (P + (size_t)(LCH - 1) * M1)
                               : (((k - 1) & 1) ? QB : QA);
    float* Qn = (k & 1) ? QB : QA;
    k_dual<MODE_PLAIN, true, MODE_LEVEL, false><<<gd, 256, 0, stream>>>(
        Qk, Qk, Qn,
        inp - (size_t)(4 << k) * DD, Qk, outp, inp,
        nullptr, nullptr, 0);
    float* tmp = inp; inp = outp; outp = tmp;
  }
  // 5. final level k=7 (uses Q_7 = QA)
  {
    const float* Q7 = QA;
    k_one<MODE_LEVEL, false><<<dim3(16, 16), 256, 0, stream>>>(
        inp - (size_t)(4 << 7) * DD, Q7, outp, inp,
        nullptr, nullptr, 0, nullptr, nullptr);
    float* tmp = inp; inp = outp; outp = tmp;
  }
  // after 8 levels result is in E0d (inp)

  // 6. batched carry-apply: hidden[b][c*8+d] = locals[d][r] + E_{c-1} @ (W^{d+1})^T
  k_one<MODE_CARRY, false><<<dim3(16, 16, LCH), 256, 0, stream>>>(
      inp - (size_t)4 * DD, P, nullptr, nullptr,
      nullptr, ids, 0, LOC, HID);

  // 7. LM head
  dim3 gl(VV / 128, (BB * TT) / 128);
  k_lmhead<<<gl, 256, 0, stream>>>(HID, LWB, lm_b, out);
}

// Round 4
// 1001.666 us; speedup vs baseline: 5.9884x; 1.7266x over previous
//
#include <hip/hip_runtime.h>
#include <hip/hip_bf16.h>
#include <stdint.h>

#define DD 1024   // hidden dim
#define BB 4      // batch
#define TT 2048   // seq len
#define VV 16000  // vocab
#define LCH 8     // chunk length
#define NR 1024   // BB*(TT/LCH) rows, r = c*4 + b
#define PADR 512  // zero pad rows before E buffers (max level shift)

typedef __bf16 bf16_t;
typedef float f32x4_t __attribute__((ext_vector_type(4)));
typedef bf16_t bf16x8_t __attribute__((ext_vector_type(8)));
typedef bf16_t bf16x4_t __attribute__((ext_vector_type(4)));

#define MODE_PLAIN 0
#define MODE_ROUND 1
#define MODE_LEVEL 2
#define MODE_CARRY 3

#define KIND_SQ 0
#define KIND_ROUND 1
#define KIND_LEVEL 2
#define KIND_CARRY 3

struct Job {
  const float* A; const float* B; float* C; const float* Cin;
  int kind; int dlt;
};
struct Jobs { Job j[8]; };

// ---------------- fp32 -> bf16 convert (lm_w) ----------------
__global__ __launch_bounds__(256) void k_cvt(const float* __restrict__ src,
                                             bf16_t* __restrict__ dst, int n4) {
  int i = blockIdx.x * blockDim.x + threadIdx.x;
  int stride = gridDim.x * blockDim.x;
  for (; i < n4; i += stride) {
    float4 v = ((const float4*)src)[i];
    union { ushort4 u; bf16_t h[4]; } p;
    p.h[0] = (bf16_t)v.x; p.h[1] = (bf16_t)v.y;
    p.h[2] = (bf16_t)v.z; p.h[3] = (bf16_t)v.w;
    ((ushort4*)dst)[i] = p.u;
  }
}

// ---------------- gather chunk-start rows into locals slab 0 ----------------
__global__ __launch_bounds__(256) void k_gather(const float* __restrict__ embed,
                                                const int* __restrict__ ids,
                                                float* __restrict__ slab0) {
  int r = blockIdx.x;  // 0..1023
  int b = r & 3, c = r >> 2;
  int id = ids[b * TT + c * LCH];
  const float4* s = (const float4*)(embed + (size_t)id * DD);
  float4* d = (float4*)(slab0 + (size_t)r * DD);
  for (int i = threadIdx.x; i < DD / 4; i += blockDim.x) d[i] = s[i];
}

// ---------------- split-write helper: fp32x4 -> NS bf16 planes ----------------
// plane stride 5120 B ( = 64 rows * 80 B ), row stride 80 B (20-bank: conflict-free)
template <int NS>
__device__ __forceinline__ void swrite(char* base, int byteoff, float4 v) {
  float r0 = v.x, r1 = v.y, r2 = v.z, r3 = v.w;
#pragma unroll
  for (int p = 0; p < NS; ++p) {
    bf16x4_t h;
    h[0] = (bf16_t)r0; h[1] = (bf16_t)r1; h[2] = (bf16_t)r2; h[3] = (bf16_t)r3;
    *(bf16x4_t*)(base + p * 5120 + byteoff) = h;
    if (p + 1 < NS) {
      r0 -= (float)h[0]; r1 -= (float)h[1]; r2 -= (float)h[2]; r3 -= (float)h[3];
    }
  }
}

// ---------------- split-bf16 MFMA GEMM body ----------------
// C = A @ B^T (NT) or A @ B (NN), fp32 in/out, NS-way bf16 split (error ~2^-8NS).
// Tile 64x64, BK=32, 4 waves each own a 32x32 quadrant (2x2 16x16 frags).
template <int NS, bool NN, int MODE>
__device__ __forceinline__ void mbody(bf16_t* __restrict__ SB, const Job& jb,
                                      const float* __restrict__ embed,
                                      const int* __restrict__ ids,
                                      bf16_t* __restrict__ hidden) {
  const float* A = jb.A;
  const float* Bm = jb.B;
  const int tid = threadIdx.x, lane = tid & 63, wave = tid >> 6;
  const int i0 = blockIdx.y * 64, j0 = blockIdx.x * 64;
  const int wm = (wave >> 1) * 32, wn = (wave & 1) * 32;
  char* Ap = (char*)SB;
  char* Bp = Ap + NS * 5120;
  const int arow = tid >> 2;              // 64 rows, 4 thr/row
  const int akb = (tid & 3) * 8;          // byte offset of 4-elem k-group
  const int bj = tid & 63, bk4 = (tid >> 6) * 4;  // NN mapping
  const int frow = lane & 15, fkb = (lane >> 4) * 16;
  f32x4_t acc[2][2] = {};

  const float* Aptr = A + (size_t)(i0 + arow) * DD + (tid & 3) * 4;
  const float* BptrNT = Bm + (size_t)(j0 + arow) * DD + (tid & 3) * 4;
  const float* BptrNN = Bm + (size_t)bk4 * DD + j0 + bj;

  float4 a0 = *(const float4*)(Aptr);
  float4 a1 = *(const float4*)(Aptr + 16);
  float4 b0, b1;
  float s0[4], s1[4];
  if (!NN) {
    b0 = *(const float4*)(BptrNT);
    b1 = *(const float4*)(BptrNT + 16);
  } else {
#pragma unroll
    for (int s = 0; s < 4; ++s) s0[s] = BptrNN[(size_t)s * DD];
#pragma unroll
    for (int s = 0; s < 4; ++s) s1[s] = BptrNN[(size_t)(16 + s) * DD];
  }

  for (int k0 = 0;;) {
    __syncthreads();  // previous iteration's frag reads complete
    swrite<NS>(Ap, arow * 80 + akb, a0);
    swrite<NS>(Ap, arow * 80 + akb + 32, a1);
    if (!NN) {
      swrite<NS>(Bp, arow * 80 + akb, b0);
      swrite<NS>(Bp, arow * 80 + akb + 32, b1);
    } else {
      // transpose-stage: 4 k-consecutive elems at fixed j -> [j][k] planes
      float4 t0; t0.x = s0[0]; t0.y = s0[1]; t0.z = s0[2]; t0.w = s0[3];
      float4 t1; t1.x = s1[0]; t1.y = s1[1]; t1.z = s1[2]; t1.w = s1[3];
      swrite<NS>(Bp, bj * 80 + bk4 * 2, t0);
      swrite<NS>(Bp, bj * 80 + bk4 * 2 + 32, t1);
    }
    __syncthreads();
    int kn = k0 + 32;
    if (kn < DD) {  // prefetch next K-tile (hides under MFMA)
      a0 = *(const float4*)(Aptr + kn);
      a1 = *(const float4*)(Aptr + kn + 16);
      if (!NN) {
        b0 = *(const float4*)(BptrNT + kn);
        b1 = *(const float4*)(BptrNT + kn + 16);
      } else {
#pragma unroll
        for (int s = 0; s < 4; ++s) s0[s] = BptrNN[(size_t)(kn + s) * DD];
#pragma unroll
        for (int s = 0; s < 4; ++s) s1[s] = BptrNN[(size_t)(kn + 16 + s) * DD];
      }
    }
    bf16x8_t af[NS][2], bfx[NS][2];
#pragma unroll
    for (int p = 0; p < NS; ++p)
#pragma unroll
      for (int mf = 0; mf < 2; ++mf) {
        af[p][mf] = *(const bf16x8_t*)(Ap + p * 5120 + (wm + mf * 16 + frow) * 80 + fkb);
        bfx[p][mf] = *(const bf16x8_t*)(Bp + p * 5120 + (wn + mf * 16 + frow) * 80 + fkb);
      }
#pragma unroll
    for (int pa = 0; pa < NS; ++pa)
#pragma unroll
      for (int pb = 0; pb < NS; ++pb) {
        if (pa + pb < NS) {  // constexpr-pruned term set: NS=2 -> 3, NS=3 -> 6
#pragma unroll
          for (int mf = 0; mf < 2; ++mf)
#pragma unroll
            for (int nf = 0; nf < 2; ++nf)
              acc[mf][nf] = __builtin_amdgcn_mfma_f32_16x16x32_bf16(
                  af[pa][mf], bfx[pb][nf], acc[mf][nf], 0, 0, 0);
        }
      }
    k0 = kn;
    if (k0 >= DD) break;
  }

  // epilogue; C/D layout: col = lane&15, row = (lane>>4)*4 + reg [m89-verified]
  const int ecol = lane & 15, er4 = (lane >> 4) * 4;
#pragma unroll
  for (int mf = 0; mf < 2; ++mf) {
#pragma unroll
    for (int nf = 0; nf < 2; ++nf) {
      const int rb = i0 + wm + mf * 16 + er4;
      const int cj = j0 + wn + nf * 16 + ecol;
#pragma unroll
      for (int rg = 0; rg < 4; ++rg) {
        const int ri = rb + rg;
        float v = acc[mf][nf][rg];
        if (MODE == MODE_PLAIN) {
          jb.C[(size_t)ri * DD + cj] = v;
        } else if (MODE == MODE_ROUND) {
          int b = ri & 3, c = ri >> 2, t = c * LCH + jb.dlt;
          v += embed[(size_t)ids[b * TT + t] * DD + cj];
          jb.C[(size_t)ri * DD + cj] = v;
        } else if (MODE == MODE_LEVEL) {
          v += jb.Cin[(size_t)ri * DD + cj];
          jb.C[(size_t)ri * DD + cj] = v;
        } else {  // MODE_CARRY
          int b = ri & 3, c = ri >> 2, t = c * LCH + jb.dlt;
          hidden[((size_t)b * TT + t) * DD + cj] =
              (bf16_t)(v + jb.Cin[(size_t)ri * DD + cj]);
        }
      }
    }
  }
}

// z-indexed multi-GEMM dispatcher
__global__ __launch_bounds__(256, 2) void k_multi(Jobs jobs,
                                                  const float* __restrict__ embed,
                                                  const int* __restrict__ ids,
                                                  bf16_t* __restrict__ hidden) {
  __shared__ __align__(16) bf16_t SB[6 * 2560];  // 30720 B: up to 3+3 planes
  const Job& jb = jobs.j[blockIdx.z];
  if (jb.kind == KIND_SQ)
    mbody<3, true, MODE_PLAIN>(SB, jb, embed, ids, hidden);
  else if (jb.kind == KIND_ROUND)
    mbody<2, false, MODE_ROUND>(SB, jb, embed, ids, hidden);
  else if (jb.kind == KIND_LEVEL)
    mbody<2, false, MODE_LEVEL>(SB, jb, embed, ids, hidden);
  else
    mbody<2, false, MODE_CARRY>(SB, jb, embed, ids, hidden);
}

// ---------------- LM head: bf16 MFMA GEMM (unchanged from round 3) ----------
__device__ __forceinline__ void gload16(const void* g, void* l) {
  __builtin_amdgcn_global_load_lds((const __attribute__((address_space(1))) void*)g,
                                   (__attribute__((address_space(3))) void*)l, 16, 0, 0);
}

__global__ __launch_bounds__(256) void k_lmhead(const bf16_t* __restrict__ Ah,
                                                const bf16_t* __restrict__ Bw,
                                                const float* __restrict__ bias,
                                                float* __restrict__ Cout) {
  __shared__ bf16_t Al[128 * 64];
  __shared__ bf16_t Bl[128 * 64];
  int orig = blockIdx.y * gridDim.x + blockIdx.x;
  int swz = (orig & 7) * 1000 + (orig >> 3);
  int bx = swz % 125, by = swz / 125;
  int m0 = by * 128, n0 = bx * 128;
  int tid = threadIdx.x;
  int wave = tid >> 6, lane = tid & 63;
  int wm = (wave >> 1) * 64, wn = (wave & 1) * 64;
  f32x4_t acc[4][4] = {};
  int frow = lane & 15;

  for (int k0 = 0; k0 < DD; k0 += 64) {
#pragma unroll
    for (int it = 0; it < 4; ++it) {
      int zb = it * 4096 + wave * 1024;
      int tpos = zb + lane * 16;
      int row = tpos >> 7;
      int scol = (tpos & 127) ^ ((row & 7) << 4);
      gload16((const char*)Ah + ((size_t)(m0 + row) * DD + k0) * 2 + scol,
              (char*)Al + zb);
      gload16((const char*)Bw + ((size_t)(n0 + row) * DD + k0) * 2 + scol,
              (char*)Bl + zb);
    }
    __syncthreads();
    bf16x8_t afr[2][4], bfr[2][4];
#pragma unroll
    for (int b = 0; b < 2; ++b) {
#pragma unroll
      for (int mf = 0; mf < 4; ++mf) {
        int r = wm + mf * 16 + frow;
        int off = (b * 64 + (lane >> 4) * 16) ^ ((r & 7) << 4);
        afr[b][mf] = *(const bf16x8_t*)((const char*)Al + r * 128 + off);
        int rn = wn + mf * 16 + frow;
        bfr[b][mf] = *(const bf16x8_t*)((const char*)Bl + rn * 128 + off);
      }
    }
#pragma unroll
    for (int b = 0; b < 2; ++b)
#pragma unroll
      for (int mf = 0; mf < 4; ++mf)
#pragma unroll
        for (int nf = 0; nf < 4; ++nf)
          acc[mf][nf] = __builtin_amdgcn_mfma_f32_16x16x32_bf16(
              afr[b][mf], bfr[b][nf], acc[mf][nf], 0, 0, 0);
    __syncthreads();
  }
  int ecol = lane & 15, erow4 = (lane >> 4) * 4;
#pragma unroll
  for (int mf = 0; mf < 4; ++mf) {
#pragma unroll
    for (int nf = 0; nf < 4; ++nf) {
      int gm = m0 + wm + mf * 16 + erow4;
      int gn = n0 + wn + nf * 16 + ecol;
      float bv = bias[gn];
#pragma unroll
      for (int reg = 0; reg < 4; ++reg)
        Cout[(size_t)(gm + reg) * VV + gn] = acc[mf][nf][reg] + bv;
    }
  }
}

// ---------------- host orchestration ----------------
extern "C" void kernel_launch(void* const* d_in, const int* in_sizes, int n_in,
                              void* d_out, int out_size, void* d_ws, size_t ws_size,
                              hipStream_t stream) {
  (void)in_sizes; (void)n_in; (void)out_size; (void)ws_size;
  const int* ids = (const int*)d_in[0];
  const float* embed = (const float*)d_in[1];
  const float* w_state = (const float*)d_in[2];
  const float* lm_w = (const float*)d_in[3];
  const float* lm_b = (const float*)d_in[4];
  float* out = (float*)d_out;

  const size_t M1 = (size_t)DD * DD;
  float* PW = (float*)d_ws;                       // 8*M1 : PW + n*M1 = W^{n+1}
  float* Q = PW + 8 * M1;                         // 7*M1 : Q+(k-1)*M1 = W^{8*2^k}
  float* LOC = Q + 7 * M1;                        // 8*M1 : locals slabs d=0..7
  float* E0 = LOC + 8 * M1;                       // (512+1024)*1024
  float* E1 = E0 + (size_t)(PADR + NR) * DD;      // (512+1024)*1024
  bf16_t* HID = (bf16_t*)(E1 + (size_t)(PADR + NR) * DD);  // 8M bf16
  bf16_t* LWB = HID + (size_t)BB * TT * DD;       // 16000*1024 bf16
  float* E0d = E0 + (size_t)PADR * DD;
  float* E1d = E1 + (size_t)PADR * DD;

  // setup
  k_cvt<<<2048, 256, 0, stream>>>(lm_w, LWB, VV * DD / 4);
  hipMemcpyAsync(PW, w_state, M1 * sizeof(float), hipMemcpyDeviceToDevice, stream);
  k_gather<<<NR, 256, 0, stream>>>(embed, ids, LOC);
  hipMemsetAsync(E0, 0, (size_t)PADR * DD * sizeof(float), stream);
  hipMemsetAsync(E1, 0, (size_t)PADR * DD * sizeof(float), stream);

  Jobs J{};
  // L1: P2 = W*W | LOC1
  J.j[0] = Job{w_state, w_state, PW + M1, nullptr, KIND_SQ, 0};
  J.j[1] = Job{LOC, w_state, LOC + M1, nullptr, KIND_ROUND, 1};
  k_multi<<<dim3(16, 16, 2), 256, 0, stream>>>(J, embed, ids, HID);
  // L2: P3 = P2*W ; P4 = P2*P2 | LOC2
  J.j[0] = Job{PW + M1, w_state, PW + 2 * M1, nullptr, KIND_SQ, 0};
  J.j[1] = Job{PW + M1, PW + M1, PW + 3 * M1, nullptr, KIND_SQ, 0};
  J.j[2] = Job{LOC + M1, w_state, LOC + 2 * M1, nullptr, KIND_ROUND, 2};
  k_multi<<<dim3(16, 16, 3), 256, 0, stream>>>(J, embed, ids, HID);
  // L3: P5..P8 | LOC3
  J.j[0] = Job{PW + 3 * M1, w_state, PW + 4 * M1, nullptr, KIND_SQ, 0};
  J.j[1] = Job{PW + 3 * M1, PW + M1, PW + 5 * M1, nullptr, KIND_SQ, 0};
  J.j[2] = Job{PW + 3 * M1, PW + 2 * M1, PW + 6 * M1, nullptr, KIND_SQ, 0};
  J.j[3] = Job{PW + 3 * M1, PW + 3 * M1, PW + 7 * M1, nullptr, KIND_SQ, 0};
  J.j[4] = Job{LOC + 2 * M1, w_state, LOC + 3 * M1, nullptr, KIND_ROUND, 3};
  k_multi<<<dim3(16, 16, 5), 256, 0, stream>>>(J, embed, ids, HID);
  // L4..L7: Q1..Q4 squarings | LOC4..LOC7
  for (int d = 4; d <= 7; ++d) {
    const float* src = (d == 4) ? (PW + 7 * M1) : (Q + (size_t)(d - 5) * M1);
    J.j[0] = Job{src, src, Q + (size_t)(d - 4) * M1, nullptr, KIND_SQ, 0};
    J.j[1] = Job{LOC + (size_t)(d - 1) * M1, w_state, LOC + (size_t)d * M1,
                 nullptr, KIND_ROUND, d};
    k_multi<<<dim3(16, 16, 2), 256, 0, stream>>>(J, embed, ids, HID);
  }
  // chunk-end scan init: E0 data = LOC slab 7
  hipMemcpyAsync(E0d, LOC + 7 * M1, M1 * sizeof(float),
                 hipMemcpyDeviceToDevice, stream);

  // L8..L15: Hillis-Steele levels (8) fused with Q5..Q7 squarings (first 3)
  float* inp = E0d;
  float* outp = E1d;
  for (int k = 0; k < 8; ++k) {
    Jobs J2{};
    int nz = 0;
    if (k <= 2) {  // Q_{k+5} = Q_{k+4}^2
      const float* src = Q + (size_t)(k + 3) * M1;
      J2.j[nz++] = Job{src, src, Q + (size_t)(k + 4) * M1, nullptr, KIND_SQ, 0};
    }
    const float* Bq = (k == 0) ? (PW + 7 * M1) : (Q + (size_t)(k - 1) * M1);
    J2.j[nz++] = Job{inp - (size_t)(4 << k) * DD, Bq, outp, inp, KIND_LEVEL, 0};
    k_multi<<<dim3(16, 16, nz), 256, 0, stream>>>(J2, embed, ids, HID);
    float* t = inp; inp = outp; outp = t;
  }
  // final prefix ends in E0d (== inp after 8 swaps)

  // L16: batched carry-apply -> hidden (bf16)
  Jobs Jc{};
  for (int d = 0; d < 8; ++d)
    Jc.j[d] = Job{inp - (size_t)4 * DD, PW + (size_t)d * M1, nullptr,
                  LOC + (size_t)d * M1, KIND_CARRY, d};
  k_multi<<<dim3(16, 16, 8), 256, 0, stream>>>(Jc, embed, ids, HID);

  // L17: LM head
  dim3 gl(VV / 128, (BB * TT) / 128);
  k_lmhead<<<gl, 256, 0, stream>>>(HID, LWB, lm_b, out);
}

// Round 5
// 900.088 us; speedup vs baseline: 6.6642x; 1.1129x over previous
//
#include <hip/hip_runtime.h>
#include <hip/hip_bf16.h>
#include <stdint.h>

#define DD 1024   // hidden dim
#define BB 4      // batch
#define TT 2048   // seq len
#define VV 16000  // vocab
#define LCH 8     // chunk length
#define NR 1024   // BB*(TT/LCH) rows, r = c*4 + b
#define PADR 512  // zero pad rows before E buffers (max level shift)
#define NPAD 16128  // lm_w rows padded to 63*256

typedef __bf16 bf16_t;
typedef float f32x4_t __attribute__((ext_vector_type(4)));
typedef bf16_t bf16x8_t __attribute__((ext_vector_type(8)));
typedef bf16_t bf16x4_t __attribute__((ext_vector_type(4)));

#define MODE_PLAIN 0
#define MODE_ROUND 1
#define MODE_LEVEL 2
#define MODE_CARRY 3

#define KIND_SQ 0
#define KIND_ROUND 1
#define KIND_LEVEL 2
#define KIND_CARRY 3

struct Job {
  const float* A; const float* B; float* C; const float* Cin;
  int kind; int dlt;
};
struct Jobs { Job j[8]; };

// ---------------- fp32 -> bf16 convert (lm_w) ----------------
__global__ __launch_bounds__(256) void k_cvt(const float* __restrict__ src,
                                             bf16_t* __restrict__ dst, int n4) {
  int i = blockIdx.x * blockDim.x + threadIdx.x;
  int stride = gridDim.x * blockDim.x;
  for (; i < n4; i += stride) {
    float4 v = ((const float4*)src)[i];
    union { ushort4 u; bf16_t h[4]; } p;
    p.h[0] = (bf16_t)v.x; p.h[1] = (bf16_t)v.y;
    p.h[2] = (bf16_t)v.z; p.h[3] = (bf16_t)v.w;
    ((ushort4*)dst)[i] = p.u;
  }
}

// ---------------- gather chunk-start rows into locals slab 0 ----------------
__global__ __launch_bounds__(256) void k_gather(const float* __restrict__ embed,
                                                const int* __restrict__ ids,
                                                float* __restrict__ slab0) {
  int r = blockIdx.x;  // 0..1023
  int b = r & 3, c = r >> 2;
  int id = ids[b * TT + c * LCH];
  const float4* s = (const float4*)(embed + (size_t)id * DD);
  float4* d = (float4*)(slab0 + (size_t)r * DD);
  for (int i = threadIdx.x; i < DD / 4; i += blockDim.x) d[i] = s[i];
}

// ---------------- split-write helper: fp32x4 -> NS bf16 planes ----------------
template <int NS>
__device__ __forceinline__ void swrite(char* base, int byteoff, float4 v) {
  float r0 = v.x, r1 = v.y, r2 = v.z, r3 = v.w;
#pragma unroll
  for (int p = 0; p < NS; ++p) {
    bf16x4_t h;
    h[0] = (bf16_t)r0; h[1] = (bf16_t)r1; h[2] = (bf16_t)r2; h[3] = (bf16_t)r3;
    *(bf16x4_t*)(base + p * 5120 + byteoff) = h;
    if (p + 1 < NS) {
      r0 -= (float)h[0]; r1 -= (float)h[1]; r2 -= (float)h[2]; r3 -= (float)h[3];
    }
  }
}

// ---------------- split-bf16 MFMA GEMM body (chain kernels) ----------------
template <int NS, bool NN, int MODE>
__device__ __forceinline__ void mbody(bf16_t* __restrict__ SB, const Job& jb,
                                      const float* __restrict__ embed,
                                      const int* __restrict__ ids,
                                      bf16_t* __restrict__ hidden) {
  const float* A = jb.A;
  const float* Bm = jb.B;
  const int tid = threadIdx.x, lane = tid & 63, wave = tid >> 6;
  const int i0 = blockIdx.y * 64, j0 = blockIdx.x * 64;
  const int wm = (wave >> 1) * 32, wn = (wave & 1) * 32;
  char* Ap = (char*)SB;
  char* Bp = Ap + NS * 5120;
  const int arow = tid >> 2;
  const int akb = (tid & 3) * 8;
  const int bj = tid & 63, bk4 = (tid >> 6) * 4;
  const int frow = lane & 15, fkb = (lane >> 4) * 16;
  f32x4_t acc[2][2] = {};

  const float* Aptr = A + (size_t)(i0 + arow) * DD + (tid & 3) * 4;
  const float* BptrNT = Bm + (size_t)(j0 + arow) * DD + (tid & 3) * 4;
  const float* BptrNN = Bm + (size_t)bk4 * DD + j0 + bj;

  float4 a0 = *(const float4*)(Aptr);
  float4 a1 = *(const float4*)(Aptr + 16);
  float4 b0, b1;
  float s0[4], s1[4];
  if (!NN) {
    b0 = *(const float4*)(BptrNT);
    b1 = *(const float4*)(BptrNT + 16);
  } else {
#pragma unroll
    for (int s = 0; s < 4; ++s) s0[s] = BptrNN[(size_t)s * DD];
#pragma unroll
    for (int s = 0; s < 4; ++s) s1[s] = BptrNN[(size_t)(16 + s) * DD];
  }

  for (int k0 = 0;;) {
    __syncthreads();
    swrite<NS>(Ap, arow * 80 + akb, a0);
    swrite<NS>(Ap, arow * 80 + akb + 32, a1);
    if (!NN) {
      swrite<NS>(Bp, arow * 80 + akb, b0);
      swrite<NS>(Bp, arow * 80 + akb + 32, b1);
    } else {
      float4 t0; t0.x = s0[0]; t0.y = s0[1]; t0.z = s0[2]; t0.w = s0[3];
      float4 t1; t1.x = s1[0]; t1.y = s1[1]; t1.z = s1[2]; t1.w = s1[3];
      swrite<NS>(Bp, bj * 80 + bk4 * 2, t0);
      swrite<NS>(Bp, bj * 80 + bk4 * 2 + 32, t1);
    }
    __syncthreads();
    int kn = k0 + 32;
    if (kn < DD) {
      a0 = *(const float4*)(Aptr + kn);
      a1 = *(const float4*)(Aptr + kn + 16);
      if (!NN) {
        b0 = *(const float4*)(BptrNT + kn);
        b1 = *(const float4*)(BptrNT + kn + 16);
      } else {
#pragma unroll
        for (int s = 0; s < 4; ++s) s0[s] = BptrNN[(size_t)(kn + s) * DD];
#pragma unroll
        for (int s = 0; s < 4; ++s) s1[s] = BptrNN[(size_t)(kn + 16 + s) * DD];
      }
    }
    bf16x8_t af[NS][2], bfx[NS][2];
#pragma unroll
    for (int p = 0; p < NS; ++p)
#pragma unroll
      for (int mf = 0; mf < 2; ++mf) {
        af[p][mf] = *(const bf16x8_t*)(Ap + p * 5120 + (wm + mf * 16 + frow) * 80 + fkb);
        bfx[p][mf] = *(const bf16x8_t*)(Bp + p * 5120 + (wn + mf * 16 + frow) * 80 + fkb);
      }
#pragma unroll
    for (int pa = 0; pa < NS; ++pa)
#pragma unroll
      for (int pb = 0; pb < NS; ++pb) {
        if (pa + pb < NS) {
#pragma unroll
          for (int mf = 0; mf < 2; ++mf)
#pragma unroll
            for (int nf = 0; nf < 2; ++nf)
              acc[mf][nf] = __builtin_amdgcn_mfma_f32_16x16x32_bf16(
                  af[pa][mf], bfx[pb][nf], acc[mf][nf], 0, 0, 0);
        }
      }
    k0 = kn;
    if (k0 >= DD) break;
  }

  const int ecol = lane & 15, er4 = (lane >> 4) * 4;
#pragma unroll
  for (int mf = 0; mf < 2; ++mf) {
#pragma unroll
    for (int nf = 0; nf < 2; ++nf) {
      const int rb = i0 + wm + mf * 16 + er4;
      const int cj = j0 + wn + nf * 16 + ecol;
#pragma unroll
      for (int rg = 0; rg < 4; ++rg) {
        const int ri = rb + rg;
        float v = acc[mf][nf][rg];
        if (MODE == MODE_PLAIN) {
          jb.C[(size_t)ri * DD + cj] = v;
        } else if (MODE == MODE_ROUND) {
          int b = ri & 3, c = ri >> 2, t = c * LCH + jb.dlt;
          v += embed[(size_t)ids[b * TT + t] * DD + cj];
          jb.C[(size_t)ri * DD + cj] = v;
        } else if (MODE == MODE_LEVEL) {
          v += jb.Cin[(size_t)ri * DD + cj];
          jb.C[(size_t)ri * DD + cj] = v;
        } else {
          int b = ri & 3, c = ri >> 2, t = c * LCH + jb.dlt;
          hidden[((size_t)b * TT + t) * DD + cj] =
              (bf16_t)(v + jb.Cin[(size_t)ri * DD + cj]);
        }
      }
    }
  }
}

__global__ __launch_bounds__(256, 2) void k_multi(Jobs jobs,
                                                  const float* __restrict__ embed,
                                                  const int* __restrict__ ids,
                                                  bf16_t* __restrict__ hidden) {
  __shared__ __align__(16) bf16_t SB[6 * 2560];
  const Job& jb = jobs.j[blockIdx.z];
  if (jb.kind == KIND_SQ)
    mbody<3, true, MODE_PLAIN>(SB, jb, embed, ids, hidden);
  else if (jb.kind == KIND_ROUND)
    mbody<2, false, MODE_ROUND>(SB, jb, embed, ids, hidden);
  else if (jb.kind == KIND_LEVEL)
    mbody<2, false, MODE_LEVEL>(SB, jb, embed, ids, hidden);
  else
    mbody<2, false, MODE_CARRY>(SB, jb, embed, ids, hidden);
}

// ---------------- LM head: 256x256 tile, BK=32, quad-buffered pipeline ------
// 8 waves (2M x 4N), per-wave C = 128x64. LDS: 4 bufs x (A 16KB + B 16KB).
// Stage 3 K-tiles ahead; counted vmcnt(8) per tile (never 0 until drain).
// LDS 64B rows, XOR swizzle c ^= ((row>>1)&3)<<4 -> frag reads conflict-free.
__device__ __forceinline__ void gload16(const void* g, void* l) {
  __builtin_amdgcn_global_load_lds((const __attribute__((address_space(1))) void*)g,
                                   (__attribute__((address_space(3))) void*)l, 16, 0, 0);
}

#define NTK 32  // K-tiles (1024/32)

__global__ __launch_bounds__(512, 2) void k_lmhead2(
    const bf16_t* __restrict__ Ah, const bf16_t* __restrict__ Bw,
    const float* __restrict__ bias, float* __restrict__ Cout) {
  __shared__ __align__(16) char LB[4 * 32768];
  const int tid = threadIdx.x, lane = tid & 63, wave = tid >> 6;
  const int wr = wave >> 2, wc = wave & 3;
  // bijective XCD swizzle: nwg = 63*32 = 2016, 2016/8 = 252
  int orig = blockIdx.y * gridDim.x + blockIdx.x;
  int swz = (orig & 7) * 252 + (orig >> 3);
  int by = swz / 63, bx = swz % 63;
  const int m0 = by * 256, n0 = bx * 256;

  const int srow = tid >> 2;        // staging row within 128-row pass
  const int scb = (tid & 3) * 16;   // staging byte col within 64B row

  auto stage = [&](int t) {
    char* buf = LB + (size_t)(t & 3) * 32768;
#pragma unroll
    for (int p = 0; p < 2; ++p) {
      int row = p * 128 + srow;
      int sw = ((row >> 1) & 3) << 4;
      gload16((const char*)Ah + ((size_t)(m0 + row) * DD + t * 32) * 2 + (scb ^ sw),
              buf + p * 8192 + wave * 1024);
      gload16((const char*)Bw + ((size_t)(n0 + row) * DD + t * 32) * 2 + (scb ^ sw),
              buf + 16384 + p * 8192 + wave * 1024);
    }
  };

  const int frow = lane & 15;
  const int c4b = (lane >> 4) * 16;
  f32x4_t acc[8][4] = {};

  // prologue: stage tiles 0..2 (12 loads/thread), wait tile0 (4 oldest)
  stage(0); stage(1); stage(2);
  asm volatile("s_waitcnt vmcnt(8)\ns_barrier" ::: "memory");

  for (int t = 0; t < NTK; ++t) {
    char* Abuf = LB + (size_t)(t & 3) * 32768;
    char* Bbuf = Abuf + 16384;
    if (t + 3 < NTK) stage(t + 3);
    bf16x8_t afr[4], bfr[4];
    // phase 0: B all 4 + A mf0..3
#pragma unroll
    for (int nf = 0; nf < 4; ++nf) {
      int r = wc * 64 + nf * 16 + frow;
      bfr[nf] = *(const bf16x8_t*)(Bbuf + r * 64 + (c4b ^ (((r >> 1) & 3) << 4)));
    }
#pragma unroll
    for (int mf = 0; mf < 4; ++mf) {
      int r = wr * 128 + mf * 16 + frow;
      afr[mf] = *(const bf16x8_t*)(Abuf + r * 64 + (c4b ^ (((r >> 1) & 3) << 4)));
    }
    __builtin_amdgcn_s_setprio(1);
#pragma unroll
    for (int mf = 0; mf < 4; ++mf)
#pragma unroll
      for (int nf = 0; nf < 4; ++nf)
        acc[mf][nf] = __builtin_amdgcn_mfma_f32_16x16x32_bf16(
            afr[mf], bfr[nf], acc[mf][nf], 0, 0, 0);
    __builtin_amdgcn_s_setprio(0);
    // phase 1: A mf4..7 (B reused in regs)
#pragma unroll
    for (int mf = 0; mf < 4; ++mf) {
      int r = wr * 128 + 64 + mf * 16 + frow;
      afr[mf] = *(const bf16x8_t*)(Abuf + r * 64 + (c4b ^ (((r >> 1) & 3) << 4)));
    }
    __builtin_amdgcn_s_setprio(1);
#pragma unroll
    for (int mf = 0; mf < 4; ++mf)
#pragma unroll
      for (int nf = 0; nf < 4; ++nf)
        acc[4 + mf][nf] = __builtin_amdgcn_mfma_f32_16x16x32_bf16(
            afr[mf], bfr[nf], acc[4 + mf][nf], 0, 0, 0);
    __builtin_amdgcn_s_setprio(0);
    // boundary: tile t+1 must be landed; allow newest {t+2,t+3} in flight
    if (t < NTK - 3) {
      asm volatile("s_waitcnt vmcnt(8)\ns_barrier" ::: "memory");
    } else if (t == NTK - 3) {
      asm volatile("s_waitcnt vmcnt(4)\ns_barrier" ::: "memory");
    } else if (t == NTK - 2) {
      asm volatile("s_waitcnt vmcnt(0)\ns_barrier" ::: "memory");
    }
  }

  const int ecol = lane & 15, er4 = (lane >> 4) * 4;
#pragma unroll
  for (int mf = 0; mf < 8; ++mf) {
#pragma unroll
    for (int nf = 0; nf < 4; ++nf) {
      int gm = m0 + wr * 128 + mf * 16 + er4;
      int gn = n0 + wc * 64 + nf * 16 + ecol;
      if (gn < VV) {
        float bv = bias[gn];
#pragma unroll
        for (int rg = 0; rg < 4; ++rg)
          Cout[(size_t)(gm + rg) * VV + gn] = acc[mf][nf][rg] + bv;
      }
    }
  }
}

// ---------------- host orchestration ----------------
extern "C" void kernel_launch(void* const* d_in, const int* in_sizes, int n_in,
                              void* d_out, int out_size, void* d_ws, size_t ws_size,
                              hipStream_t stream) {
  (void)in_sizes; (void)n_in; (void)out_size; (void)ws_size;
  const int* ids = (const int*)d_in[0];
  const float* embed = (const float*)d_in[1];
  const float* w_state = (const float*)d_in[2];
  const float* lm_w = (const float*)d_in[3];
  const float* lm_b = (const float*)d_in[4];
  float* out = (float*)d_out;

  const size_t M1 = (size_t)DD * DD;
  float* PW = (float*)d_ws;                       // 8*M1 : PW + n*M1 = W^{n+1}
  float* Q = PW + 8 * M1;                         // 7*M1
  float* LOC = Q + 7 * M1;                        // 8*M1 : locals slabs d=0..7
  float* E0 = LOC + 8 * M1;
  float* E1 = E0 + (size_t)(PADR + NR) * DD;
  bf16_t* HID = (bf16_t*)(E1 + (size_t)(PADR + NR) * DD);  // 8192x1024 bf16
  bf16_t* LWB = HID + (size_t)BB * TT * DD;       // NPAD x 1024 bf16 (padded)
  float* E0d = E0 + (size_t)PADR * DD;
  float* E1d = E1 + (size_t)PADR * DD;

  // setup
  k_cvt<<<2048, 256, 0, stream>>>(lm_w, LWB, VV * DD / 4);
  hipMemsetAsync(LWB + (size_t)VV * DD, 0,
                 (size_t)(NPAD - VV) * DD * sizeof(bf16_t), stream);
  hipMemcpyAsync(PW, w_state, M1 * sizeof(float), hipMemcpyDeviceToDevice, stream);
  k_gather<<<NR, 256, 0, stream>>>(embed, ids, LOC);
  hipMemsetAsync(E0, 0, (size_t)PADR * DD * sizeof(float), stream);
  hipMemsetAsync(E1, 0, (size_t)PADR * DD * sizeof(float), stream);

  Jobs J{};
  // L1: P2 = W*W | LOC1
  J.j[0] = Job{w_state, w_state, PW + M1, nullptr, KIND_SQ, 0};
  J.j[1] = Job{LOC, w_state, LOC + M1, nullptr, KIND_ROUND, 1};
  k_multi<<<dim3(16, 16, 2), 256, 0, stream>>>(J, embed, ids, HID);
  // L2: P3 ; P4 | LOC2
  J.j[0] = Job{PW + M1, w_state, PW + 2 * M1, nullptr, KIND_SQ, 0};
  J.j[1] = Job{PW + M1, PW + M1, PW + 3 * M1, nullptr, KIND_SQ, 0};
  J.j[2] = Job{LOC + M1, w_state, LOC + 2 * M1, nullptr, KIND_ROUND, 2};
  k_multi<<<dim3(16, 16, 3), 256, 0, stream>>>(J, embed, ids, HID);
  // L3: P5..P8 | LOC3
  J.j[0] = Job{PW + 3 * M1, w_state, PW + 4 * M1, nullptr, KIND_SQ, 0};
  J.j[1] = Job{PW + 3 * M1, PW + M1, PW + 5 * M1, nullptr, KIND_SQ, 0};
  J.j[2] = Job{PW + 3 * M1, PW + 2 * M1, PW + 6 * M1, nullptr, KIND_SQ, 0};
  J.j[3] = Job{PW + 3 * M1, PW + 3 * M1, PW + 7 * M1, nullptr, KIND_SQ, 0};
  J.j[4] = Job{LOC + 2 * M1, w_state, LOC + 3 * M1, nullptr, KIND_ROUND, 3};
  k_multi<<<dim3(16, 16, 5), 256, 0, stream>>>(J, embed, ids, HID);
  // L4..L7: Q1..Q4 | LOC4..LOC7
  for (int d = 4; d <= 7; ++d) {
    const float* src = (d == 4) ? (PW + 7 * M1) : (Q + (size_t)(d - 5) * M1);
    J.j[0] = Job{src, src, Q + (size_t)(d - 4) * M1, nullptr, KIND_SQ, 0};
    J.j[1] = Job{LOC + (size_t)(d - 1) * M1, w_state, LOC + (size_t)d * M1,
                 nullptr, KIND_ROUND, d};
    k_multi<<<dim3(16, 16, 2), 256, 0, stream>>>(J, embed, ids, HID);
  }
  hipMemcpyAsync(E0d, LOC + 7 * M1, M1 * sizeof(float),
                 hipMemcpyDeviceToDevice, stream);

  // L8..L15: scan levels fused with Q5..Q7 squarings
  float* inp = E0d;
  float* outp = E1d;
  for (int k = 0; k < 8; ++k) {
    Jobs J2{};
    int nz = 0;
    if (k <= 2) {
      const float* src = Q + (size_t)(k + 3) * M1;
      J2.j[nz++] = Job{src, src, Q + (size_t)(k + 4) * M1, nullptr, KIND_SQ, 0};
    }
    const float* Bq = (k == 0) ? (PW + 7 * M1) : (Q + (size_t)(k - 1) * M1);
    J2.j[nz++] = Job{inp - (size_t)(4 << k) * DD, Bq, outp, inp, KIND_LEVEL, 0};
    k_multi<<<dim3(16, 16, nz), 256, 0, stream>>>(J2, embed, ids, HID);
    float* t = inp; inp = outp; outp = t;
  }

  // L16: batched carry-apply -> hidden (bf16)
  Jobs Jc{};
  for (int d = 0; d < 8; ++d)
    Jc.j[d] = Job{inp - (size_t)4 * DD, PW + (size_t)d * M1, nullptr,
                  LOC + (size_t)d * M1, KIND_CARRY, d};
  k_multi<<<dim3(16, 16, 8), 256, 0, stream>>>(Jc, embed, ids, HID);

  // L17: LM head (256x256 pipelined MFMA)
  dim3 gl(NPAD / 256, (BB * TT) / 256);
  k_lmhead2<<<gl, 512, 0, stream>>>(HID, LWB, lm_b, out);
}

// Round 6
// 888.929 us; speedup vs baseline: 6.7479x; 1.0126x over previous
//
#include <hip/hip_runtime.h>
#include <hip/hip_bf16.h>
#include <stdint.h>

#define DD 1024   // hidden dim
#define BB 4      // batch
#define TT 2048   // seq len
#define VV 16000  // vocab
#define LCH 8     // chunk length
#define NR 1024   // BB*(TT/LCH) rows, r = c*4 + b
#define PADR 512  // zero pad rows before E buffers
#define NPAD 16128
#define M1C ((size_t)DD * DD)
#define ESTR ((PADR + NR) * DD)

typedef __bf16 bf16_t;
typedef float f32x4_t __attribute__((ext_vector_type(4)));
typedef bf16_t bf16x8_t __attribute__((ext_vector_type(8)));
typedef bf16_t bf16x4_t __attribute__((ext_vector_type(4)));

#define KIND_SQ 0
#define KIND_ROUND 1
#define KIND_LEVEL 2
#define KIND_CARRY 3

// ======================= shared helpers =======================
__device__ __forceinline__ void gload16(const void* g, void* l) {
  __builtin_amdgcn_global_load_lds((const __attribute__((address_space(1))) void*)g,
                                   (__attribute__((address_space(3))) void*)l, 16, 0, 0);
}

__device__ __forceinline__ void split3(float v, bf16_t& h0, bf16_t& h1, bf16_t& h2) {
  h0 = (bf16_t)v; float r = v - (float)h0;
  h1 = (bf16_t)r; h2 = (bf16_t)(r - (float)h1);
}

// ---------------- fp32 -> bf16 convert (lm_w) ----------------
__global__ __launch_bounds__(256) void k_cvt(const float* __restrict__ src,
                                             bf16_t* __restrict__ dst, int n4) {
  int i = blockIdx.x * blockDim.x + threadIdx.x;
  int stride = gridDim.x * blockDim.x;
  for (; i < n4; i += stride) {
    float4 v = ((const float4*)src)[i];
    union { ushort4 u; bf16_t h[4]; } p;
    p.h[0] = (bf16_t)v.x; p.h[1] = (bf16_t)v.y;
    p.h[2] = (bf16_t)v.z; p.h[3] = (bf16_t)v.w;
    ((ushort4*)dst)[i] = p.u;
  }
}

// ======================= NEW bf16-plane chain path =======================
struct Job {
  const void* A; const void* B; void* C; void* C2; const void* Cin;
  int kind, dlt, astr, cinstr, cstr;
};
struct Jobs { Job j[8]; };

// W fp32 -> 3 row planes + 3 col planes bf16
__global__ __launch_bounds__(256) void k_prepW(const float* __restrict__ W,
                                               bf16_t* __restrict__ Wrow,
                                               bf16_t* __restrict__ Wcol) {
  __shared__ float t[32][33];
  int bx = blockIdx.x * 32, by = blockIdx.y * 32;
  int tx = threadIdx.x & 31, ty = threadIdx.x >> 5;
#pragma unroll
  for (int q = 0; q < 4; ++q) {
    int r = by + ty + q * 8;
    float v = W[(size_t)r * DD + bx + tx];
    t[ty + q * 8][tx] = v;
    bf16_t h0, h1, h2; split3(v, h0, h1, h2);
    size_t o = (size_t)r * DD + bx + tx;
    Wrow[o] = h0; Wrow[o + M1C] = h1; Wrow[o + 2 * M1C] = h2;
  }
  __syncthreads();
#pragma unroll
  for (int q = 0; q < 4; ++q) {
    float v = t[tx][ty + q * 8];  // = W[by+tx][bx+ty+q*8]
    bf16_t h0, h1, h2; split3(v, h0, h1, h2);
    size_t o = (size_t)(bx + ty + q * 8) * DD + by + tx;  // Wcol[j][i] = W[i][j]
    Wcol[o] = h0; Wcol[o + M1C] = h1; Wcol[o + 2 * M1C] = h2;
  }
}

// gather chunk-start embed rows -> LOC slab0 (2-plane bf16)
__global__ __launch_bounds__(256) void k_gather2(const float* __restrict__ embed,
                                                 const int* __restrict__ ids,
                                                 bf16_t* __restrict__ slab0) {
  int r = blockIdx.x;  // 0..1023
  int b = r & 3, c = r >> 2;
  int id = ids[b * TT + c * LCH];
  const float4* s = (const float4*)(embed + (size_t)id * DD);
  bf16_t* p0 = slab0 + (size_t)r * DD;
  bf16_t* p1 = p0 + M1C;  // plane stride NR*DD == M1C
  for (int i = threadIdx.x; i < DD / 4; i += blockDim.x) {
    float4 v = s[i];
    union { ushort4 u; bf16_t h[4]; } a, bq;
    a.h[0] = (bf16_t)v.x; bq.h[0] = (bf16_t)(v.x - (float)a.h[0]);
    a.h[1] = (bf16_t)v.y; bq.h[1] = (bf16_t)(v.y - (float)a.h[1]);
    a.h[2] = (bf16_t)v.z; bq.h[2] = (bf16_t)(v.z - (float)a.h[2]);
    a.h[3] = (bf16_t)v.w; bq.h[3] = (bf16_t)(v.w - (float)a.h[3]);
    ((ushort4*)p0)[i] = a.u;
    ((ushort4*)p1)[i] = bq.u;
  }
}

// bf16-plane GEMM body. SQ6: A=3 row planes, B=3 col planes, 6 terms, BK=32.
// state: A=2 planes, B planes 0,1 (of 3-plane power), 3 terms, BK=64.
// 64x64 tile, 4 waves x 32x32 (2x2 16x16 frags). gload_lds staging with
// source-preswizzle (rule #21); frag reads conflict-free (2 lanes/bank).
template <bool SQ6>
__device__ __forceinline__ void tbody(char* SB, const Job& jb,
                                      const float* __restrict__ embed,
                                      const int* __restrict__ ids) {
  constexpr int BK = SQ6 ? 32 : 64;
  constexpr int NP = SQ6 ? 3 : 2;
  constexpr int ROWB = BK * 2;       // LDS row bytes
  constexpr int PTB = 64 * ROWB;     // plane tile bytes (4096 / 8192)
  const bf16_t* Ab = (const bf16_t*)jb.A;
  const bf16_t* Bb = (const bf16_t*)jb.B;
  const int tid = threadIdx.x, lane = tid & 63, wave = tid >> 6;
  const int i0 = blockIdx.y * 64, j0 = blockIdx.x * 64;
  const int wm = (wave >> 1) * 32, wn = (wave & 1) * 32;
  char* BL = SB + NP * PTB;
  const int frow = lane & 15, fq = lane >> 4;
  f32x4_t acc[2][2] = {};

  for (int kt = 0; kt < DD / BK; ++kt) {
    const int k0 = kt * BK;
    __syncthreads();  // prior tile's frag reads complete
    if (SQ6) {
      const int row = tid >> 2, g = tid & 3;
      const int gs = g ^ ((row >> 1) & 3);
#pragma unroll
      for (int p = 0; p < 3; ++p) {
        gload16(Ab + (size_t)p * jb.astr + (size_t)(i0 + row) * DD + k0 + gs * 8,
                SB + p * PTB + wave * 1024);
        gload16(Bb + (size_t)p * M1C + (size_t)(j0 + row) * DD + k0 + gs * 8,
                BL + p * PTB + wave * 1024);
      }
    } else {
      const int row8 = tid >> 3, g = tid & 7;
#pragma unroll
      for (int p = 0; p < 2; ++p)
#pragma unroll
        for (int h = 0; h < 2; ++h) {
          int row = h * 32 + row8;
          int gs = g ^ (row & 7);
          gload16(Ab + (size_t)p * jb.astr + (size_t)(i0 + row) * DD + k0 + gs * 8,
                  SB + p * PTB + h * 4096 + wave * 1024);
          gload16(Bb + (size_t)p * M1C + (size_t)(j0 + row) * DD + k0 + gs * 8,
                  BL + p * PTB + h * 4096 + wave * 1024);
        }
    }
    asm volatile("s_waitcnt vmcnt(0)" ::: "memory");
    __syncthreads();

    if (SQ6) {
      bf16x8_t af[3][2], bfx[3][2];
#pragma unroll
      for (int p = 0; p < 3; ++p)
#pragma unroll
        for (int mf = 0; mf < 2; ++mf) {
          int ra = wm + mf * 16 + frow;
          af[p][mf] = *(const bf16x8_t*)(SB + p * PTB + ra * 64 +
                                         ((fq ^ ((ra >> 1) & 3)) << 4));
          int rb = wn + mf * 16 + frow;
          bfx[p][mf] = *(const bf16x8_t*)(BL + p * PTB + rb * 64 +
                                          ((fq ^ ((rb >> 1) & 3)) << 4));
        }
      const int TA[6] = {0, 0, 1, 0, 2, 1}, TB[6] = {0, 1, 0, 2, 0, 1};
#pragma unroll
      for (int tix = 0; tix < 6; ++tix)
#pragma unroll
        for (int mf = 0; mf < 2; ++mf)
#pragma unroll
          for (int nf = 0; nf < 2; ++nf)
            acc[mf][nf] = __builtin_amdgcn_mfma_f32_16x16x32_bf16(
                af[TA[tix]][mf], bfx[TB[tix]][nf], acc[mf][nf], 0, 0, 0);
    } else {
      bf16x8_t af[2][2][2], bfx[2][2][2];
#pragma unroll
      for (int p = 0; p < 2; ++p)
#pragma unroll
        for (int mf = 0; mf < 2; ++mf)
#pragma unroll
          for (int ks = 0; ks < 2; ++ks) {
            int ra = wm + mf * 16 + frow;
            af[p][mf][ks] = *(const bf16x8_t*)(SB + p * PTB + ra * 128 +
                                               (((ks * 4 + fq) ^ (ra & 7)) << 4));
            int rb = wn + mf * 16 + frow;
            bfx[p][mf][ks] = *(const bf16x8_t*)(BL + p * PTB + rb * 128 +
                                                (((ks * 4 + fq) ^ (rb & 7)) << 4));
          }
#pragma unroll
      for (int ks = 0; ks < 2; ++ks)
#pragma unroll
        for (int mf = 0; mf < 2; ++mf)
#pragma unroll
          for (int nf = 0; nf < 2; ++nf) {
            acc[mf][nf] = __builtin_amdgcn_mfma_f32_16x16x32_bf16(
                af[0][mf][ks], bfx[0][nf][ks], acc[mf][nf], 0, 0, 0);
            acc[mf][nf] = __builtin_amdgcn_mfma_f32_16x16x32_bf16(
                af[0][mf][ks], bfx[1][nf][ks], acc[mf][nf], 0, 0, 0);
            acc[mf][nf] = __builtin_amdgcn_mfma_f32_16x16x32_bf16(
                af[1][mf][ks], bfx[0][nf][ks], acc[mf][nf], 0, 0, 0);
          }
    }
  }

  // epilogue; C/D layout: col = lane&15, row = (lane>>4)*4 + reg [m89-verified]
  const int ecol = lane & 15, er4 = fq * 4;
#pragma unroll
  for (int mf = 0; mf < 2; ++mf) {
#pragma unroll
    for (int nf = 0; nf < 2; ++nf) {
      const int rb0 = i0 + wm + mf * 16 + er4;
      const int cj = j0 + wn + nf * 16 + ecol;
      if (SQ6) {
        bf16_t* Cr = (bf16_t*)jb.C;
        bf16x4_t c0, c1, c2;
#pragma unroll
        for (int rg = 0; rg < 4; ++rg) {
          float v = acc[mf][nf][rg];
          bf16_t h0, h1, h2; split3(v, h0, h1, h2);
          size_t o = (size_t)(rb0 + rg) * DD + cj;
          Cr[o] = h0; Cr[o + M1C] = h1; Cr[o + 2 * M1C] = h2;
          c0[rg] = h0; c1[rg] = h1; c2[rg] = h2;
        }
        if (jb.C2) {  // transposed (col-plane) copy for future squarings
          bf16_t* Cc = (bf16_t*)jb.C2;
          size_t o = (size_t)cj * DD + rb0;
          *(bf16x4_t*)(Cc + o) = c0;
          *(bf16x4_t*)(Cc + o + M1C) = c1;
          *(bf16x4_t*)(Cc + o + 2 * M1C) = c2;
        }
      } else if (jb.kind == KIND_ROUND) {
        bf16_t* Cr = (bf16_t*)jb.C;
#pragma unroll
        for (int rg = 0; rg < 4; ++rg) {
          int ri = rb0 + rg;
          int b = ri & 3, c = ri >> 2, t = c * LCH + jb.dlt;
          float v = acc[mf][nf][rg] + embed[(size_t)ids[b * TT + t] * DD + cj];
          bf16_t h0 = (bf16_t)v;
          size_t o = (size_t)ri * DD + cj;
          Cr[o] = h0; Cr[o + jb.cstr] = (bf16_t)(v - (float)h0);
        }
      } else if (jb.kind == KIND_LEVEL) {
        bf16_t* Cr = (bf16_t*)jb.C;
        const bf16_t* Ci = (const bf16_t*)jb.Cin;
#pragma unroll
        for (int rg = 0; rg < 4; ++rg) {
          int ri = rb0 + rg;
          size_t o = (size_t)ri * DD + cj;
          float cin = (float)Ci[o] + (float)Ci[o + jb.cinstr];
          float v = acc[mf][nf][rg] + cin;
          bf16_t h0 = (bf16_t)v;
          Cr[o] = h0; Cr[o + jb.cstr] = (bf16_t)(v - (float)h0);
        }
      } else {  // KIND_CARRY -> hidden bf16
        bf16_t* Hid = (bf16_t*)jb.C;
        const bf16_t* Ci = (const bf16_t*)jb.Cin;
#pragma unroll
        for (int rg = 0; rg < 4; ++rg) {
          int ri = rb0 + rg;
          int b = ri & 3, c = ri >> 2, t = c * LCH + jb.dlt;
          size_t o = (size_t)ri * DD + cj;
          float cin = (float)Ci[o] + (float)Ci[o + jb.cinstr];
          Hid[((size_t)b * TT + t) * DD + cj] = (bf16_t)(acc[mf][nf][rg] + cin);
        }
      }
    }
  }
}

__global__ __launch_bounds__(256, 3) void k_multi2(Jobs jobs,
                                                   const float* __restrict__ embed,
                                                   const int* __restrict__ ids) {
  __shared__ __align__(16) char SB[32768];
  const Job& jb = jobs.j[blockIdx.z];
  if (jb.kind == KIND_SQ) tbody<true>(SB, jb, embed, ids);
  else tbody<false>(SB, jb, embed, ids);
}

// ======================= OLD fallback path (round-5, verified) =======================
struct JobF {
  const float* A; const float* B; float* C; const float* Cin;
  int kind; int dlt;
};
struct JobsF { JobF j[8]; };

__global__ __launch_bounds__(256) void k_gatherF(const float* __restrict__ embed,
                                                 const int* __restrict__ ids,
                                                 float* __restrict__ slab0) {
  int r = blockIdx.x;
  int b = r & 3, c = r >> 2;
  int id = ids[b * TT + c * LCH];
  const float4* s = (const float4*)(embed + (size_t)id * DD);
  float4* d = (float4*)(slab0 + (size_t)r * DD);
  for (int i = threadIdx.x; i < DD / 4; i += blockDim.x) d[i] = s[i];
}

template <int NS>
__device__ __forceinline__ void swrite(char* base, int byteoff, float4 v) {
  float r0 = v.x, r1 = v.y, r2 = v.z, r3 = v.w;
#pragma unroll
  for (int p = 0; p < NS; ++p) {
    bf16x4_t h;
    h[0] = (bf16_t)r0; h[1] = (bf16_t)r1; h[2] = (bf16_t)r2; h[3] = (bf16_t)r3;
    *(bf16x4_t*)(base + p * 5120 + byteoff) = h;
    if (p + 1 < NS) {
      r0 -= (float)h[0]; r1 -= (float)h[1]; r2 -= (float)h[2]; r3 -= (float)h[3];
    }
  }
}

template <int NS, bool NN, int MODE>  // MODE: 0 plain,1 round,2 level,3 carry
__device__ __forceinline__ void mbodyF(bf16_t* __restrict__ SBb, const JobF& jb,
                                       const float* __restrict__ embed,
                                       const int* __restrict__ ids,
                                       bf16_t* __restrict__ hidden) {
  const float* A = jb.A;
  const float* Bm = jb.B;
  const int tid = threadIdx.x, lane = tid & 63, wave = tid >> 6;
  const int i0 = blockIdx.y * 64, j0 = blockIdx.x * 64;
  const int wm = (wave >> 1) * 32, wn = (wave & 1) * 32;
  char* Ap = (char*)SBb;
  char* Bp = Ap + NS * 5120;
  const int arow = tid >> 2;
  const int akb = (tid & 3) * 8;
  const int bj = tid & 63, bk4 = (tid >> 6) * 4;
  const int frow = lane & 15, fkb = (lane >> 4) * 16;
  f32x4_t acc[2][2] = {};

  const float* Aptr = A + (size_t)(i0 + arow) * DD + (tid & 3) * 4;
  const float* BptrNT = Bm + (size_t)(j0 + arow) * DD + (tid & 3) * 4;
  const float* BptrNN = Bm + (size_t)bk4 * DD + j0 + bj;

  float4 a0 = *(const float4*)(Aptr);
  float4 a1 = *(const float4*)(Aptr + 16);
  float4 b0, b1;
  float s0[4], s1[4];
  if (!NN) {
    b0 = *(const float4*)(BptrNT);
    b1 = *(const float4*)(BptrNT + 16);
  } else {
#pragma unroll
    for (int s = 0; s < 4; ++s) s0[s] = BptrNN[(size_t)s * DD];
#pragma unroll
    for (int s = 0; s < 4; ++s) s1[s] = BptrNN[(size_t)(16 + s) * DD];
  }

  for (int k0 = 0;;) {
    __syncthreads();
    swrite<NS>(Ap, arow * 80 + akb, a0);
    swrite<NS>(Ap, arow * 80 + akb + 32, a1);
    if (!NN) {
      swrite<NS>(Bp, arow * 80 + akb, b0);
      swrite<NS>(Bp, arow * 80 + akb + 32, b1);
    } else {
      float4 t0; t0.x = s0[0]; t0.y = s0[1]; t0.z = s0[2]; t0.w = s0[3];
      float4 t1; t1.x = s1[0]; t1.y = s1[1]; t1.z = s1[2]; t1.w = s1[3];
      swrite<NS>(Bp, bj * 80 + bk4 * 2, t0);
      swrite<NS>(Bp, bj * 80 + bk4 * 2 + 32, t1);
    }
    __syncthreads();
    int kn = k0 + 32;
    if (kn < DD) {
      a0 = *(const float4*)(Aptr + kn);
      a1 = *(const float4*)(Aptr + kn + 16);
      if (!NN) {
        b0 = *(const float4*)(BptrNT + kn);
        b1 = *(const float4*)(BptrNT + kn + 16);
      } else {
#pragma unroll
        for (int s = 0; s < 4; ++s) s0[s] = BptrNN[(size_t)(kn + s) * DD];
#pragma unroll
        for (int s = 0; s < 4; ++s) s1[s] = BptrNN[(size_t)(kn + 16 + s) * DD];
      }
    }
    bf16x8_t af[NS][2], bfx[NS][2];
#pragma unroll
    for (int p = 0; p < NS; ++p)
#pragma unroll
      for (int mf = 0; mf < 2; ++mf) {
        af[p][mf] = *(const bf16x8_t*)(Ap + p * 5120 + (wm + mf * 16 + frow) * 80 + fkb);
        bfx[p][mf] = *(const bf16x8_t*)(Bp + p * 5120 + (wn + mf * 16 + frow) * 80 + fkb);
      }
#pragma unroll
    for (int pa = 0; pa < NS; ++pa)
#pragma unroll
      for (int pb = 0; pb < NS; ++pb) {
        if (pa + pb < NS) {
#pragma unroll
          for (int mf = 0; mf < 2; ++mf)
#pragma unroll
            for (int nf = 0; nf < 2; ++nf)
              acc[mf][nf] = __builtin_amdgcn_mfma_f32_16x16x32_bf16(
                  af[pa][mf], bfx[pb][nf], acc[mf][nf], 0, 0, 0);
        }
      }
    k0 = kn;
    if (k0 >= DD) break;
  }

  const int ecol = lane & 15, er4 = (lane >> 4) * 4;
#pragma unroll
  for (int mf = 0; mf < 2; ++mf) {
#pragma unroll
    for (int nf = 0; nf < 2; ++nf) {
      const int rb = i0 + wm + mf * 16 + er4;
      const int cj = j0 + wn + nf * 16 + ecol;
#pragma unroll
      for (int rg = 0; rg < 4; ++rg) {
        const int ri = rb + rg;
        float v = acc[mf][nf][rg];
        if (MODE == 0) {
          jb.C[(size_t)ri * DD + cj] = v;
        } else if (MODE == 1) {
          int b = ri & 3, c = ri >> 2, t = c * LCH + jb.dlt;
          v += embed[(size_t)ids[b * TT + t] * DD + cj];
          jb.C[(size_t)ri * DD + cj] = v;
        } else if (MODE == 2) {
          v += jb.Cin[(size_t)ri * DD + cj];
          jb.C[(size_t)ri * DD + cj] = v;
        } else {
          int b = ri & 3, c = ri >> 2, t = c * LCH + jb.dlt;
          hidden[((size_t)b * TT + t) * DD + cj] =
              (bf16_t)(v + jb.Cin[(size_t)ri * DD + cj]);
        }
      }
    }
  }
}

__global__ __launch_bounds__(256, 2) void k_multiF(JobsF jobs,
                                                   const float* __restrict__ embed,
                                                   const int* __restrict__ ids,
                                                   bf16_t* __restrict__ hidden) {
  __shared__ __align__(16) bf16_t SBb[6 * 2560];
  const JobF& jb = jobs.j[blockIdx.z];
  if (jb.kind == KIND_SQ)
    mbodyF<3, true, 0>(SBb, jb, embed, ids, hidden);
  else if (jb.kind == KIND_ROUND)
    mbodyF<2, false, 1>(SBb, jb, embed, ids, hidden);
  else if (jb.kind == KIND_LEVEL)
    mbodyF<2, false, 2>(SBb, jb, embed, ids, hidden);
  else
    mbodyF<2, false, 3>(SBb, jb, embed, ids, hidden);
}

// ======================= LM head (round-5, verified) =======================
#define NTK 32

__global__ __launch_bounds__(512, 2) void k_lmhead2(
    const bf16_t* __restrict__ Ah, const bf16_t* __restrict__ Bw,
    const float* __restrict__ bias, float* __restrict__ Cout) {
  __shared__ __align__(16) char LB[4 * 32768];
  const int tid = threadIdx.x, lane = tid & 63, wave = tid >> 6;
  const int wr = wave >> 2, wc = wave & 3;
  int orig = blockIdx.y * gridDim.x + blockIdx.x;
  int swz = (orig & 7) * 252 + (orig >> 3);
  int by = swz / 63, bx = swz % 63;
  const int m0 = by * 256, n0 = bx * 256;

  const int srow = tid >> 2;
  const int scb = (tid & 3) * 16;

  auto stage = [&](int t) {
    char* buf = LB + (size_t)(t & 3) * 32768;
#pragma unroll
    for (int p = 0; p < 2; ++p) {
      int row = p * 128 + srow;
      int sw = ((row >> 1) & 3) << 4;
      gload16((const char*)Ah + ((size_t)(m0 + row) * DD + t * 32) * 2 + (scb ^ sw),
              buf + p * 8192 + wave * 1024);
      gload16((const char*)Bw + ((size_t)(n0 + row) * DD + t * 32) * 2 + (scb ^ sw),
              buf + 16384 + p * 8192 + wave * 1024);
    }
  };

  const int frow = lane & 15;
  const int c4b = (lane >> 4) * 16;
  f32x4_t acc[8][4] = {};

  stage(0); stage(1); stage(2);
  asm volatile("s_waitcnt vmcnt(8)\ns_barrier" ::: "memory");

  for (int t = 0; t < NTK; ++t) {
    char* Abuf = LB + (size_t)(t & 3) * 32768;
    char* Bbuf = Abuf + 16384;
    if (t + 3 < NTK) stage(t + 3);
    bf16x8_t afr[4], bfr[4];
#pragma unroll
    for (int nf = 0; nf < 4; ++nf) {
      int r = wc * 64 + nf * 16 + frow;
      bfr[nf] = *(const bf16x8_t*)(Bbuf + r * 64 + (c4b ^ (((r >> 1) & 3) << 4)));
    }
#pragma unroll
    for (int mf = 0; mf < 4; ++mf) {
      int r = wr * 128 + mf * 16 + frow;
      afr[mf] = *(const bf16x8_t*)(Abuf + r * 64 + (c4b ^ (((r >> 1) & 3) << 4)));
    }
    __builtin_amdgcn_s_setprio(1);
#pragma unroll
    for (int mf = 0; mf < 4; ++mf)
#pragma unroll
      for (int nf = 0; nf < 4; ++nf)
        acc[mf][nf] = __builtin_amdgcn_mfma_f32_16x16x32_bf16(
            afr[mf], bfr[nf], acc[mf][nf], 0, 0, 0);
    __builtin_amdgcn_s_setprio(0);
#pragma unroll
    for (int mf = 0; mf < 4; ++mf) {
      int r = wr * 128 + 64 + mf * 16 + frow;
      afr[mf] = *(const bf16x8_t*)(Abuf + r * 64 + (c4b ^ (((r >> 1) & 3) << 4)));
    }
    __builtin_amdgcn_s_setprio(1);
#pragma unroll
    for (int mf = 0; mf < 4; ++mf)
#pragma unroll
      for (int nf = 0; nf < 4; ++nf)
        acc[4 + mf][nf] = __builtin_amdgcn_mfma_f32_16x16x32_bf16(
            afr[mf], bfr[nf], acc[4 + mf][nf], 0, 0, 0);
    __builtin_amdgcn_s_setprio(0);
    if (t < NTK - 3) {
      asm volatile("s_waitcnt vmcnt(8)\ns_barrier" ::: "memory");
    } else if (t == NTK - 3) {
      asm volatile("s_waitcnt vmcnt(4)\ns_barrier" ::: "memory");
    } else if (t == NTK - 2) {
      asm volatile("s_waitcnt vmcnt(0)\ns_barrier" ::: "memory");
    }
  }

  const int ecol = lane & 15, er4 = (lane >> 4) * 4;
#pragma unroll
  for (int mf = 0; mf < 8; ++mf) {
#pragma unroll
    for (int nf = 0; nf < 4; ++nf) {
      int gm = m0 + wr * 128 + mf * 16 + er4;
      int gn = n0 + wc * 64 + nf * 16 + ecol;
      if (gn < VV) {
        float bv = bias[gn];
#pragma unroll
        for (int rg = 0; rg < 4; ++rg)
          Cout[(size_t)(gm + rg) * VV + gn] = acc[mf][nf][rg] + bv;
      }
    }
  }
}

// ======================= host orchestration =======================
static void run_new(const int* ids, const float* embed, const float* w_state,
                    const float* lm_w, const float* lm_b, float* out,
                    void* d_ws, hipStream_t stream) {
  const size_t M1 = M1C;
  bf16_t* w = (bf16_t*)d_ws;
  bf16_t* Wr = w; w += 3 * M1;
  bf16_t* Wc = w; w += 3 * M1;
  bf16_t* Pr = w; w += 7 * 3 * M1;   // Pr(n) = Pr + (n-2)*3*M1, n=2..8
  bf16_t* Pc2 = w; w += 3 * M1;
  bf16_t* Pc3 = w; w += 3 * M1;
  bf16_t* Pc4 = w; w += 3 * M1;
  bf16_t* Pc8 = w; w += 3 * M1;
  bf16_t* Qr = w; w += 7 * 3 * M1;   // Qr(j) = Qr + j*3*M1, j=0..6
  bf16_t* Qc = w; w += 6 * 3 * M1;   // Qc(j), j=0..5
  bf16_t* LOCb = w; w += 8 * 2 * M1; // slab d at +d*2*M1, plane stride M1
  bf16_t* E0 = w; w += 2 * (size_t)ESTR;
  bf16_t* E1 = w; w += 2 * (size_t)ESTR;
  bf16_t* HID = w; w += (size_t)BB * TT * DD;
  bf16_t* LWB = w; w += (size_t)NPAD * DD;

  auto PrN = [&](int n) { return Pr + (size_t)(n - 2) * 3 * M1; };
  auto QrN = [&](int j) { return Qr + (size_t)j * 3 * M1; };
  auto QcN = [&](int j) { return Qc + (size_t)j * 3 * M1; };

  // setup
  k_cvt<<<2048, 256, 0, stream>>>(lm_w, LWB, VV * DD / 4);
  hipMemsetAsync(LWB + (size_t)VV * DD, 0,
                 (size_t)(NPAD - VV) * DD * sizeof(bf16_t), stream);
  k_prepW<<<dim3(32, 32), 256, 0, stream>>>(w_state, Wr, Wc);
  k_gather2<<<NR, 256, 0, stream>>>(embed, ids, LOCb);
  hipMemsetAsync(E0, 0, 2 * (size_t)ESTR * sizeof(bf16_t), stream);
  hipMemsetAsync(E1, 0, 2 * (size_t)ESTR * sizeof(bf16_t), stream);

  const int AM1 = (int)M1;
  auto SQJ = [&](const bf16_t* Arow, const bf16_t* Bcol, bf16_t* Crow, bf16_t* Ccol) {
    return Job{Arow, Bcol, Crow, Ccol, nullptr, KIND_SQ, 0, AM1, 0, 0};
  };
  auto RDJ = [&](int d) {
    return Job{LOCb + (size_t)(d - 1) * 2 * M1, Wr, LOCb + (size_t)d * 2 * M1,
               nullptr, nullptr, KIND_ROUND, d, AM1, 0, AM1};
  };

  Jobs J{};
  // L1: P2 = W*W | LOC1
  J.j[0] = SQJ(Wr, Wc, PrN(2), Pc2);
  J.j[1] = RDJ(1);
  k_multi2<<<dim3(16, 16, 2), 256, 0, stream>>>(J, embed, ids);
  // L2: P3 = P2*W ; P4 = P2*P2 | LOC2
  J.j[0] = SQJ(PrN(2), Wc, PrN(3), Pc3);
  J.j[1] = SQJ(PrN(2), Pc2, PrN(4), Pc4);
  J.j[2] = RDJ(2);
  k_multi2<<<dim3(16, 16, 3), 256, 0, stream>>>(J, embed, ids);
  // L3: P5..P8 | LOC3
  J.j[0] = SQJ(PrN(4), Wc, PrN(5), nullptr);
  J.j[1] = SQJ(PrN(4), Pc2, PrN(6), nullptr);
  J.j[2] = SQJ(PrN(4), Pc3, PrN(7), nullptr);
  J.j[3] = SQJ(PrN(4), Pc4, PrN(8), Pc8);
  J.j[4] = RDJ(3);
  k_multi2<<<dim3(16, 16, 5), 256, 0, stream>>>(J, embed, ids);
  // L4..L7: Q0..Q3 | LOC4..LOC7
  for (int d = 4; d <= 7; ++d) {
    int j = d - 4;  // produce Qj
    if (j == 0) J.j[0] = SQJ(PrN(8), Pc8, QrN(0), QcN(0));
    else J.j[0] = SQJ(QrN(j - 1), QcN(j - 1), QrN(j), QcN(j));
    J.j[1] = RDJ(d);
    k_multi2<<<dim3(16, 16, 2), 256, 0, stream>>>(J, embed, ids);
  }
  // E0 data = LOC slab 7
  for (int p = 0; p < 2; ++p)
    hipMemcpyAsync(E0 + (size_t)p * ESTR + (size_t)PADR * DD,
                   LOCb + 7 * 2 * M1 + (size_t)p * M1, M1 * sizeof(bf16_t),
                   hipMemcpyDeviceToDevice, stream);

  // L8..L15: Hillis-Steele levels fused with Q4..Q6 squarings
  bf16_t* inpD = E0 + (size_t)PADR * DD;
  bf16_t* outD = E1 + (size_t)PADR * DD;
  for (int k = 0; k < 8; ++k) {
    Jobs J2{};
    int nz = 0;
    if (k <= 2)  // Q_{k+4} = Q_{k+3}^2
      J2.j[nz++] = SQJ(QrN(k + 3), QcN(k + 3), QrN(k + 4), (k <= 1) ? QcN(k + 4) : nullptr);
    const bf16_t* Bq = (k == 0) ? PrN(8) : QrN(k - 1);
    J2.j[nz++] = Job{inpD - (size_t)(4 << k) * DD, Bq, outD, nullptr, inpD,
                     KIND_LEVEL, 0, (int)ESTR, (int)ESTR, (int)ESTR};
    k_multi2<<<dim3(16, 16, nz), 256, 0, stream>>>(J2, embed, ids);
    bf16_t* t = inpD; inpD = outD; outD = t;
  }
  // final prefix back in E0 (inpD)

  // L16: batched carry-apply -> hidden
  Jobs Jc{};
  for (int d = 0; d < 8; ++d) {
    const bf16_t* Bd = (d == 0) ? Wr : PrN(d + 1);
    Jc.j[d] = Job{inpD - (size_t)4 * DD, Bd, HID, nullptr,
                  LOCb + (size_t)d * 2 * M1, KIND_CARRY, d, (int)ESTR, AM1, 0};
  }
  k_multi2<<<dim3(16, 16, 8), 256, 0, stream>>>(Jc, embed, ids);

  // LM head
  dim3 gl(NPAD / 256, (BB * TT) / 256);
  k_lmhead2<<<gl, 512, 0, stream>>>(HID, LWB, lm_b, out);
}

static void run_old(const int* ids, const float* embed, const float* w_state,
                    const float* lm_w, const float* lm_b, float* out,
                    void* d_ws, hipStream_t stream) {
  const size_t M1 = M1C;
  float* PW = (float*)d_ws;
  float* Q = PW + 8 * M1;
  float* LOC = Q + 7 * M1;
  float* E0 = LOC + 8 * M1;
  float* E1 = E0 + (size_t)(PADR + NR) * DD;
  bf16_t* HID = (bf16_t*)(E1 + (size_t)(PADR + NR) * DD);
  bf16_t* LWB = HID + (size_t)BB * TT * DD;
  float* E0d = E0 + (size_t)PADR * DD;
  float* E1d = E1 + (size_t)PADR * DD;

  k_cvt<<<2048, 256, 0, stream>>>(lm_w, LWB, VV * DD / 4);
  hipMemsetAsync(LWB + (size_t)VV * DD, 0,
                 (size_t)(NPAD - VV) * DD * sizeof(bf16_t), stream);
  hipMemcpyAsync(PW, w_state, M1 * sizeof(float), hipMemcpyDeviceToDevice, stream);
  k_gatherF<<<NR, 256, 0, stream>>>(embed, ids, LOC);
  hipMemsetAsync(E0, 0, (size_t)PADR * DD * sizeof(float), stream);
  hipMemsetAsync(E1, 0, (size_t)PADR * DD * sizeof(float), stream);

  JobsF J{};
  J.j[0] = JobF{w_state, w_state, PW + M1, nullptr, KIND_SQ, 0};
  J.j[1] = JobF{LOC, w_state, LOC + M1, nullptr, KIND_ROUND, 1};
  k_multiF<<<dim3(16, 16, 2), 256, 0, stream>>>(J, embed, ids, HID);
  J.j[0] = JobF{PW + M1, w_state, PW + 2 * M1, nullptr, KIND_SQ, 0};
  J.j[1] = JobF{PW + M1, PW + M1, PW + 3 * M1, nullptr, KIND_SQ, 0};
  J.j[2] = JobF{LOC + M1, w_state, LOC + 2 * M1, nullptr, KIND_ROUND, 2};
  k_multiF<<<dim3(16, 16, 3), 256, 0, stream>>>(J, embed, ids, HID);
  J.j[0] = JobF{PW + 3 * M1, w_state, PW + 4 * M1, nullptr, KIND_SQ, 0};
  J.j[1] = JobF{PW + 3 * M1, PW + M1, PW + 5 * M1, nullptr, KIND_SQ, 0};
  J.j[2] = JobF{PW + 3 * M1, PW + 2 * M1, PW + 6 * M1, nullptr, KIND_SQ, 0};
  J.j[3] = JobF{PW + 3 * M1, PW + 3 * M1, PW + 7 * M1, nullptr, KIND_SQ, 0};
  J.j[4] = JobF{LOC + 2 * M1, w_state, LOC + 3 * M1, nullptr, KIND_ROUND, 3};
  k_multiF<<<dim3(16, 16, 5), 256, 0, stream>>>(J, embed, ids, HID);
  for (int d = 4; d <= 7; ++d) {
    const float* src = (d == 4) ? (PW + 7 * M1) : (Q + (size_t)(d - 5) * M1);
    J.j[0] = JobF{src, src, Q + (size_t)(d - 4) * M1, nullptr, KIND_SQ, 0};
    J.j[1] = JobF{LOC + (size_t)(d - 1) * M1, w_state, LOC + (size_t)d * M1,
                  nullptr, KIND_ROUND, d};
    k_multiF<<<dim3(16, 16, 2), 256, 0, stream>>>(J, embed, ids, HID);
  }
  hipMemcpyAsync(E0d, LOC + 7 * M1, M1 * sizeof(float),
                 hipMemcpyDeviceToDevice, stream);

  float* inp = E0d;
  float* outp = E1d;
  for (int k = 0; k < 8; ++k) {
    JobsF J2{};
    int nz = 0;
    if (k <= 2) {
      const float* src = Q + (size_t)(k + 3) * M1;
      J2.j[nz++] = JobF{src, src, Q + (size_t)(k + 4) * M1, nullptr, KIND_SQ, 0};
    }
    const float* Bq = (k == 0) ? (PW + 7 * M1) : (Q + (size_t)(k - 1) * M1);
    J2.j[nz++] = JobF{inp - (size_t)(4 << k) * DD, Bq, outp, inp, KIND_LEVEL, 0};
    k_multiF<<<dim3(16, 16, nz), 256, 0, stream>>>(J2, embed, ids, HID);
    float* t = inp; inp = outp; outp = t;
  }

  JobsF Jc{};
  for (int d = 0; d < 8; ++d)
    Jc.j[d] = JobF{inp - (size_t)4 * DD, PW + (size_t)d * M1, nullptr,
                   LOC + (size_t)d * M1, KIND_CARRY, d};
  k_multiF<<<dim3(16, 16, 8), 256, 0, stream>>>(Jc, embed, ids, HID);

  dim3 gl(NPAD / 256, (BB * TT) / 256);
  k_lmhead2<<<gl, 512, 0, stream>>>(HID, LWB, lm_b, out);
}

extern "C" void kernel_launch(void* const* d_in, const int* in_sizes, int n_in,
                              void* d_out, int out_size, void* d_ws, size_t ws_size,
                              hipStream_t stream) {
  (void)in_sizes; (void)n_in; (void)out_size;
  const int* ids = (const int*)d_in[0];
  const float* embed = (const float*)d_in[1];
  const float* w_state = (const float*)d_in[2];
  const float* lm_w = (const float*)d_in[3];
  const float* lm_b = (const float*)d_in[4];
  float* out = (float*)d_out;

  // new-path footprint (bf16 elems): W 6 + Pr 21 + Pc 12 + Qr 21 + Qc 18
  // + LOC 16 = 94*M1; E 2*2*ESTR; HID; LWB
  const size_t needNew =
      (94 * M1C + 4 * (size_t)ESTR + (size_t)BB * TT * DD + (size_t)NPAD * DD) *
      sizeof(bf16_t);
  if (ws_size >= needNew)
    run_new(ids, embed, w_state, lm_w, lm_b, out, d_ws, stream);
  else
    run_old(ids, embed, w_state, lm_w, lm_b, out, d_ws, stream);
}